// Round 9
// baseline (1518.498 us; speedup 1.0000x reference)
//
#include <hip/hip_runtime.h>
#include <cstddef>

// B=64, T=512, H=256. Float inputs fp32 (runtime-detected, bf16 fallback).
// Output fp32: [out_s (B*T), out_e (B*T)].
// ws layout (bytes): see kernel_launch.

static __device__ __forceinline__ float b2f(unsigned short u) {
  return __uint_as_float(((unsigned)u) << 16);
}
static __device__ __forceinline__ float blo(unsigned w) { return __uint_as_float(w << 16); }
static __device__ __forceinline__ float bhi(unsigned w) { return __uint_as_float(w & 0xffff0000u); }
static __device__ __forceinline__ unsigned short f2b(float f) {
  unsigned u = __float_as_uint(f);
  u += 0x7fffu + ((u >> 16) & 1u);  // RNE
  return (unsigned short)(u >> 16);
}
// adaptive input loads (md: 0=bf16 data, 1=fp32 data)
static __device__ __forceinline__ float ldf(const void* b, size_t i, int md) {
  return md ? ((const float*)b)[i] : b2f(((const unsigned short*)b)[i]);
}
static __device__ __forceinline__ unsigned short ldb(const void* b, size_t i, int md) {
  return md ? f2b(((const float*)b)[i]) : ((const unsigned short*)b)[i];
}

// MFMA fragment types (guide §3: bf16 16x16x32 -> 8 bf16 in/4 fp32 out)
typedef short bfrag __attribute__((ext_vector_type(8)));
typedef float f32x4 __attribute__((ext_vector_type(4)));

static __device__ __forceinline__ f32x4 sel4(int q, f32x4 a0, f32x4 a1, f32x4 a2, f32x4 a3) {
  return q == 0 ? a0 : (q == 1 ? a1 : (q == 2 ? a2 : a3));
}

// ---------------- dtype detection ----------------
__global__ void k_detect(const void* __restrict__ fact, int* __restrict__ mode) {
  int tid = threadIdx.x;  // 256
  const unsigned short* u = (const unsigned short*)fact;
  float v = fabsf(b2f(u[2 * tid]));
  if (!(v == v)) v = 1e30f;
  for (int o = 32; o > 0; o >>= 1) v = fmaxf(v, __shfl_xor(v, o));
  __shared__ float red[4];
  int wave = tid >> 6, lane = tid & 63;
  if (lane == 0) red[wave] = v;
  __syncthreads();
  if (tid == 0) {
    float m = fmaxf(fmaxf(red[0], red[1]), fmaxf(red[2], red[3]));
    mode[0] = (m > 1e4f) ? 1 : 0;
  }
}

// ---------------- prep: combined weights + packed Ur/Uh ----------------
__global__ void k_prep_w(const void* __restrict__ W1,
                         const void* __restrict__ Wr,
                         const void* __restrict__ Wh,
                         const void* __restrict__ Ur,
                         const void* __restrict__ Uh,
                         const int* __restrict__ mode,
                         float* __restrict__ WK2,
                         unsigned* __restrict__ Urp,
                         unsigned* __restrict__ Uhp) {
  int md = *mode;
  int idx = blockIdx.x * 256 + threadIdx.x;  // 0..65535
  int i = idx >> 8, j = idx & 255;
  WK2[0 * 65536 + idx] = ldf(W1, idx, md);
  WK2[1 * 65536 + idx] = ldf(W1, (size_t)(768 + i) * 256 + j, md) + ldf(W1, (size_t)(1024 + i) * 256 + j, md);
  WK2[2 * 65536 + idx] = ldf(W1, (size_t)(1280 + i) * 256 + j, md) + ldf(W1, (size_t)(1536 + i) * 256 + j, md);
  WK2[3 * 65536 + idx] = ldf(Wr, idx, md);
  WK2[4 * 65536 + idx] = ldf(Wh, idx, md);
  if (i < 128) {
    Urp[idx] = (unsigned)ldb(Ur, (size_t)(2 * i) * 256 + j, md) |
               ((unsigned)ldb(Ur, (size_t)(2 * i + 1) * 256 + j, md) << 16);
    Uhp[idx] = (unsigned)ldb(Uh, (size_t)(2 * i) * 256 + j, md) |
               ((unsigned)ldb(Uh, (size_t)(2 * i + 1) * 256 + j, md) << 16);
  }
}

// ---------------- prep: q-dependent vectors ----------------
__global__ void k_prep_q(const void* __restrict__ q,
                         const void* __restrict__ W1,
                         const void* __restrict__ b1,
                         const void* __restrict__ Ws,
                         const void* __restrict__ bs,
                         const void* __restrict__ We,
                         const void* __restrict__ be,
                         const int* __restrict__ mode,
                         float* __restrict__ qw1,
                         float* __restrict__ qs,
                         float* __restrict__ qe) {
  __shared__ float qsh[256];
  __shared__ float reds[4], rede[4];
  int md = *mode;
  int b = blockIdx.x, tid = threadIdx.x;
  float qv = ldf(q, (size_t)b * 256 + tid, md);
  qsh[tid] = qv;
  __syncthreads();
  float acc = ldf(b1, tid, md);
  for (int i = 0; i < 256; ++i) {
    float w = ldf(W1, (size_t)(256 + i) * 256 + tid, md) + ldf(W1, (size_t)(512 + i) * 256 + tid, md);
    acc = fmaf(qsh[i], w, acc);
  }
  qw1[b * 256 + tid] = acc;
  float ps = qv * ldf(Ws, tid, md);
  float pe = qv * ldf(We, tid, md);
  for (int o = 32; o > 0; o >>= 1) { ps += __shfl_down(ps, o); pe += __shfl_down(pe, o); }
  int wave = tid >> 6, lane = tid & 63;
  if (lane == 0) { reds[wave] = ps; rede[wave] = pe; }
  __syncthreads();
  if (tid == 0) {
    qs[b] = ldf(bs, 0, md) + reds[0] + reds[1] + reds[2] + reds[3];
    qe[b] = ldf(be, 0, md) + rede[0] + rede[1] + rede[2] + rede[3];
  }
}

// ---------------- main GEMM: att pre-softmax + xr/xh ----------------
__launch_bounds__(256, 2)
__global__ void k_main(const void* __restrict__ fact,
                       const void* __restrict__ q,
                       const float* __restrict__ WK2,
                       const float* __restrict__ qw1,
                       const void* __restrict__ W2,
                       const void* __restrict__ b2v,
                       const void* __restrict__ br,
                       const void* __restrict__ bh,
                       const int* __restrict__ mode,
                       float* __restrict__ att,
                       unsigned* __restrict__ xrh) {
  __shared__ __align__(16) float sfT[256 * 20];
  __shared__ __align__(16) float sqT[256 * 20];
  __shared__ __align__(16) float saT[256 * 20];
  __shared__ float wsc[4 * 16];
  int md = *mode;
  int blk = blockIdx.x;
  int b = blk >> 5, t0 = (blk & 31) * 16;
  int tid = threadIdx.x;
  float qv = ldf(q, (size_t)b * 256 + tid, md);
  for (int r = 0; r < 16; ++r) {
    float f = ldf(fact, ((size_t)(b * 512 + t0 + r)) * 256 + tid, md);
    sfT[tid * 20 + r] = f;
    sqT[tid * 20 + r] = f * qv;
    saT[tid * 20 + r] = fabsf(f - qv);
  }
  __syncthreads();
  int jq = tid >> 2, rq = tid & 3;
  float u[4][4] = {{0}}, ar[4][4] = {{0}}, ah[4][4] = {{0}};
  const float* w0 = WK2 + jq * 4;
  const float* w1 = w0 + 65536;
  const float* w2 = w0 + 2 * 65536;
  const float* w3 = w0 + 3 * 65536;
  const float* w4 = w0 + 4 * 65536;
  for (int i = 0; i < 256; ++i) {
    float4 wf = *(const float4*)(w0 + i * 256);
    float4 wq = *(const float4*)(w1 + i * 256);
    float4 wa = *(const float4*)(w2 + i * 256);
    float4 wr4 = *(const float4*)(w3 + i * 256);
    float4 wh4 = *(const float4*)(w4 + i * 256);
    float4 s1 = *(const float4*)(sfT + i * 20 + rq * 4);
    float4 s2 = *(const float4*)(sqT + i * 20 + rq * 4);
    float4 s3 = *(const float4*)(saT + i * 20 + rq * 4);
    float s1a[4] = {s1.x, s1.y, s1.z, s1.w};
    float s2a[4] = {s2.x, s2.y, s2.z, s2.w};
    float s3a[4] = {s3.x, s3.y, s3.z, s3.w};
    float wfa[4] = {wf.x, wf.y, wf.z, wf.w};
    float wqa[4] = {wq.x, wq.y, wq.z, wq.w};
    float waa[4] = {wa.x, wa.y, wa.z, wa.w};
    float wra[4] = {wr4.x, wr4.y, wr4.z, wr4.w};
    float wha[4] = {wh4.x, wh4.y, wh4.z, wh4.w};
#pragma unroll
    for (int rr = 0; rr < 4; ++rr) {
#pragma unroll
      for (int jj = 0; jj < 4; ++jj) {
        u[rr][jj] = fmaf(s1a[rr], wfa[jj], u[rr][jj]);
        u[rr][jj] = fmaf(s2a[rr], wqa[jj], u[rr][jj]);
        u[rr][jj] = fmaf(s3a[rr], waa[jj], u[rr][jj]);
        ar[rr][jj] = fmaf(s1a[rr], wra[jj], ar[rr][jj]);
        ah[rr][jj] = fmaf(s1a[rr], wha[jj], ah[rr][jj]);
      }
    }
  }
  float qwv[4], w2v[4], brv[4], bhv[4];
#pragma unroll
  for (int jj = 0; jj < 4; ++jj) {
    int j = jq * 4 + jj;
    qwv[jj] = qw1[b * 256 + j];
    w2v[jj] = ldf(W2, j, md);
    brv[jj] = ldf(br, j, md);
    bhv[jj] = ldf(bh, j, md);
  }
  float patt[4];
#pragma unroll
  for (int rr = 0; rr < 4; ++rr) {
    float p = 0.f;
#pragma unroll
    for (int jj = 0; jj < 4; ++jj) {
      float hid = tanhf(u[rr][jj] + qwv[jj]);
      p = fmaf(hid, w2v[jj], p);
    }
    p += __shfl_down(p, 4);
    p += __shfl_down(p, 8);
    p += __shfl_down(p, 16);
    p += __shfl_down(p, 32);
    patt[rr] = p;
  }
  int wave = tid >> 6, lane = tid & 63;
  if (lane < 4) {
#pragma unroll
    for (int rr = 0; rr < 4; ++rr) wsc[wave * 16 + lane * 4 + rr] = patt[rr];
  }
  __syncthreads();
  if (tid < 16) {
    float s = wsc[tid] + wsc[16 + tid] + wsc[32 + tid] + wsc[48 + tid];
    att[b * 512 + t0 + tid] = s + ldf(b2v, 0, md);
  }
#pragma unroll
  for (int rr = 0; rr < 4; ++rr) {
    int t = t0 + rq * 4 + rr;
    unsigned vv[4];
#pragma unroll
    for (int jj = 0; jj < 4; ++jj) {
      unsigned lo = f2b(ar[rr][jj] + brv[jj]);
      unsigned hi = f2b(ah[rr][jj] + bhv[jj]);
      vv[jj] = lo | (hi << 16);
    }
    uint4 v;
    v.x = vv[0]; v.y = vv[1]; v.z = vv[2]; v.w = vv[3];
    *(uint4*)(xrh + ((size_t)(b * 512 + t)) * 256 + jq * 4) = v;
  }
}

// ---------------- softmax over T per batch ----------------
__global__ void k_softmax(const float* __restrict__ att, float* __restrict__ g) {
  __shared__ float red[8];
  int b = blockIdx.x, tid = threadIdx.x;  // 512 threads
  float v = att[b * 512 + tid];
  float m = v;
  for (int o = 32; o > 0; o >>= 1) m = fmaxf(m, __shfl_xor(m, o));
  int wave = tid >> 6, lane = tid & 63;
  if (lane == 0) red[wave] = m;
  __syncthreads();
  m = red[0];
#pragma unroll
  for (int w = 1; w < 8; ++w) m = fmaxf(m, red[w]);
  float e = __expf(v - m);
  float s = e;
  for (int o = 32; o > 0; o >>= 1) s += __shfl_xor(s, o);
  __syncthreads();
  if (lane == 0) red[wave] = s;
  __syncthreads();
  s = red[0] + red[1] + red[2] + red[3] + red[4] + red[5] + red[6] + red[7];
  g[b * 512 + tid] = e / s;
}

// ---------------- MFMA GRU scan: 4 batches per block, 16 blocks ----------------
// 256 threads = 4 waves, 1/SIMD (weights need ~256 VGPRs). Wave wv owns cols
// [wv*64, wv*64+64) as 4 N-tiles. Per step, per phase: D[16x16] = A(h) x B(U)
// chained over 8 K-chunks via v_mfma_f32_16x16x32_bf16.
//   A[m][k]: m=lane&15, k=quad*8+j  (h rows duplicated m&3 -> D rows are
//            copies of batches 0-3 in every quad)
//   B[k][n]: n=lane&15, k=quad*8+j  (== Urp/Uhp k-pair packing)
//   C/D:     col=lane&15, row=quad*4+reg -> batch = reg in every quad
// Owner lane (quad,n16) = col wv*64+quad*16+n16, handles batches 0-3 with
// fp32 master h in registers. h/rh bf16 rows stride 272 (2-way banks = free).
// x staged 8 steps (32KB) w/ register prefetch; e flushed every 8 steps.
__launch_bounds__(256, 1)
__global__ void k_scan(const unsigned* __restrict__ Urp,
                       const unsigned* __restrict__ Uhp,
                       const unsigned* __restrict__ xrh,
                       const float* __restrict__ g,
                       const int* __restrict__ input_len,
                       unsigned short* __restrict__ ep) {
  __shared__ __align__(16) unsigned short hB[4 * 272];
  __shared__ __align__(16) unsigned short rhB[4 * 272];
  __shared__ float gsh[4 * 512];
  __shared__ __align__(16) unsigned xb[8 * 4 * 256];        // 32 KB
  __shared__ __align__(16) unsigned short eb[8 * 4 * 256];  // 16 KB
  int b0 = blockIdx.x * 4;
  int tid = threadIdx.x;
  int wv = tid >> 6, lane = tid & 63;
  int n16 = lane & 15, quad = lane >> 4;
  // B-fragments in registers: [tile][kc][w]
  unsigned br_[4][8][4], bh_[4][8][4];
#pragma unroll
  for (int tile = 0; tile < 4; ++tile) {
    int col = wv * 64 + tile * 16 + n16;
#pragma unroll
    for (int kc = 0; kc < 8; ++kc) {
#pragma unroll
      for (int w = 0; w < 4; ++w) {
        int p = kc * 16 + quad * 4 + w;
        br_[tile][kc][w] = Urp[(size_t)p * 256 + col];
        bh_[tile][kc][w] = Uhp[(size_t)p * 256 + col];
      }
    }
  }
  for (int i = tid; i < 2048; i += 256)
    gsh[i] = g[(size_t)(b0 + (i >> 9)) * 512 + (i & 511)];
  for (int i = tid; i < 4 * 272; i += 256) { hB[i] = 0; rhB[i] = 0; }
  int len[4];
#pragma unroll
  for (int m = 0; m < 4; ++m) len[m] = input_len[b0 + m];
  float hm[4] = {0.f, 0.f, 0.f, 0.f};  // master h for owned col, batches 0-3
  int cq = wv * 64 + quad * 16 + n16;  // owned column
  // x chunk 0 preload into registers (8 uint4)
  uint4 pf[8];
#pragma unroll
  for (int k = 0; k < 8; ++k) {
    int i = tid + k * 256;
    int s = i >> 8, rem = i & 255, m = rem >> 6, jc = rem & 63;
    pf[k] = ((const uint4*)(xrh + ((size_t)(b0 + m) * 512 + s) * 256))[jc];
  }
  __syncthreads();
  unsigned xcc[4] = {0u, 0u, 0u, 0u};
  for (int t = 0; t < 512; ++t) {
    int tt = t & 7;
    if (tt == 0) {
#pragma unroll
      for (int k = 0; k < 8; ++k) ((uint4*)xb)[tid + k * 256] = pf[k];
      __syncthreads();
      if (t < 504) {
        int tb = (t >> 3) + 1;
#pragma unroll
        for (int k = 0; k < 8; ++k) {
          int i = tid + k * 256;
          int s = i >> 8, rem = i & 255, m = rem >> 6, jc = rem & 63;
          pf[k] = ((const uint4*)(xrh + ((size_t)(b0 + m) * 512 + tb * 8 + s) * 256))[jc];
        }
      }
    }
    // ---- phase A: rpre = h @ Ur ----
    f32x4 za = {0.f, 0.f, 0.f, 0.f};
    f32x4 aA0 = za, aA1 = za, aA2 = za, aA3 = za;
#pragma unroll
    for (int kc = 0; kc < 8; ++kc) {
      uint4 av = *(const uint4*)((const char*)hB + (n16 & 3) * 544 + kc * 64 + quad * 16);
      bfrag af = __builtin_bit_cast(bfrag, av);
      uint4 b0v = {br_[0][kc][0], br_[0][kc][1], br_[0][kc][2], br_[0][kc][3]};
      uint4 b1v = {br_[1][kc][0], br_[1][kc][1], br_[1][kc][2], br_[1][kc][3]};
      uint4 b2v = {br_[2][kc][0], br_[2][kc][1], br_[2][kc][2], br_[2][kc][3]};
      uint4 b3v = {br_[3][kc][0], br_[3][kc][1], br_[3][kc][2], br_[3][kc][3]};
      aA0 = __builtin_amdgcn_mfma_f32_16x16x32_bf16(af, __builtin_bit_cast(bfrag, b0v), aA0, 0, 0, 0);
      aA1 = __builtin_amdgcn_mfma_f32_16x16x32_bf16(af, __builtin_bit_cast(bfrag, b1v), aA1, 0, 0, 0);
      aA2 = __builtin_amdgcn_mfma_f32_16x16x32_bf16(af, __builtin_bit_cast(bfrag, b2v), aA2, 0, 0, 0);
      aA3 = __builtin_amdgcn_mfma_f32_16x16x32_bf16(af, __builtin_bit_cast(bfrag, b3v), aA3, 0, 0, 0);
    }
    {
      f32x4 my = sel4(quad, aA0, aA1, aA2, aA3);
#pragma unroll
      for (int m = 0; m < 4; ++m) xcc[m] = xb[((tt * 4 + m) << 8) + cq];
#pragma unroll
      for (int m = 0; m < 4; ++m) {
        float r = 1.f / (1.f + __expf(-(my[m] + blo(xcc[m]))));
        rhB[m * 272 + cq] = f2b(r * hm[m]);
      }
    }
    __syncthreads();
    // ---- phase B: hpre = (r*h) @ Uh ----
    f32x4 aB0 = za, aB1 = za, aB2 = za, aB3 = za;
#pragma unroll
    for (int kc = 0; kc < 8; ++kc) {
      uint4 av = *(const uint4*)((const char*)rhB + (n16 & 3) * 544 + kc * 64 + quad * 16);
      bfrag af = __builtin_bit_cast(bfrag, av);
      uint4 b0v = {bh_[0][kc][0], bh_[0][kc][1], bh_[0][kc][2], bh_[0][kc][3]};
      uint4 b1v = {bh_[1][kc][0], bh_[1][kc][1], bh_[1][kc][2], bh_[1][kc][3]};
      uint4 b2v = {bh_[2][kc][0], bh_[2][kc][1], bh_[2][kc][2], bh_[2][kc][3]};
      uint4 b3v = {bh_[3][kc][0], bh_[3][kc][1], bh_[3][kc][2], bh_[3][kc][3]};
      aB0 = __builtin_amdgcn_mfma_f32_16x16x32_bf16(af, __builtin_bit_cast(bfrag, b0v), aB0, 0, 0, 0);
      aB1 = __builtin_amdgcn_mfma_f32_16x16x32_bf16(af, __builtin_bit_cast(bfrag, b1v), aB1, 0, 0, 0);
      aB2 = __builtin_amdgcn_mfma_f32_16x16x32_bf16(af, __builtin_bit_cast(bfrag, b2v), aB2, 0, 0, 0);
      aB3 = __builtin_amdgcn_mfma_f32_16x16x32_bf16(af, __builtin_bit_cast(bfrag, b3v), aB3, 0, 0, 0);
    }
    {
      f32x4 myc = sel4(quad, aB0, aB1, aB2, aB3);
#pragma unroll
      for (int m = 0; m < 4; ++m) {
        float xcl = fminf(fmaxf(myc[m] + bhi(xcc[m]), -15.f), 15.f);
        float exv = __expf(2.f * xcl);
        float hc = (exv - 1.f) / (exv + 1.f);
        float gt = gsh[m * 512 + t];
        bool valid = t < len[m];
        float hn = hm[m] + gt * (hc - hm[m]);
        hm[m] = valid ? hn : hm[m];
        hB[m * 272 + cq] = f2b(hm[m]);
        eb[((tt * 4 + m) << 8) + cq] = f2b(valid ? hm[m] : 0.f);
      }
    }
    __syncthreads();
    if (tt == 7) {
#pragma unroll
      for (int k = 0; k < 4; ++k) {
        int i = tid + k * 256;  // uint4 idx, 1024 total
        uint4 ev = ((const uint4*)eb)[i];
        int sm = i >> 5, jc = i & 31;
        int s = sm >> 2, m = sm & 3;
        ((uint4*)(ep + ((size_t)(b0 + m) * 512 + (t - 7 + s)) * 256))[jc] = ev;
      }
    }
  }
}

// ---------------- final dense: out_s/out_e (fp32 output) ----------------
__global__ void k_out(const unsigned short* __restrict__ ep,
                      const void* __restrict__ Ws,
                      const void* __restrict__ We,
                      const float* __restrict__ qs,
                      const float* __restrict__ qe,
                      const int* __restrict__ mode,
                      float* __restrict__ out) {
  int md = *mode;
  int tid = threadIdx.x;
  int wave = tid >> 6, lane = tid & 63;
  int row = blockIdx.x * 4 + wave;  // (b,t) flat, 0..32767
  const unsigned short* er = ep + (size_t)row * 256 + lane * 4;
  float f0 = b2f(er[0]), f1 = b2f(er[1]), f2 = b2f(er[2]), f3 = b2f(er[3]);
  int n = 256 + lane * 4;
  float s = f0 * ldf(Ws, n, md) + f1 * ldf(Ws, n + 1, md) + f2 * ldf(Ws, n + 2, md) + f3 * ldf(Ws, n + 3, md);
  float e = f0 * ldf(We, n, md) + f1 * ldf(We, n + 1, md) + f2 * ldf(We, n + 2, md) + f3 * ldf(We, n + 3, md);
  for (int o = 32; o > 0; o >>= 1) { s += __shfl_down(s, o); e += __shfl_down(e, o); }
  if (lane == 0) {
    int b = row >> 9;
    out[row] = tanhf(qs[b] + s);
    out[32768 + row] = tanhf(qe[b] + e);
  }
}

extern "C" void kernel_launch(void* const* d_in, const int* in_sizes, int n_in,
                              void* d_out, int out_size, void* d_ws, size_t ws_size,
                              hipStream_t stream) {
  const void* q    = d_in[0];
  const void* fact = d_in[1];
  const int* ilen  = (const int*)d_in[2];
  const void* W1   = d_in[3];
  const void* b1   = d_in[4];
  const void* W2   = d_in[5];
  const void* b2v  = d_in[6];
  const void* Wr   = d_in[7];
  const void* Ur   = d_in[8];
  const void* br   = d_in[9];
  const void* Wh   = d_in[10];
  const void* Uh   = d_in[11];
  const void* bh   = d_in[12];
  const void* Ws   = d_in[13];
  const void* bs   = d_in[14];
  const void* We   = d_in[15];
  const void* be   = d_in[16];

  char* w = (char*)d_ws;
  float*    WK2 = (float*)(w);
  unsigned* Urp = (unsigned*)(w + 1310720);
  unsigned* Uhp = (unsigned*)(w + 1441792);
  float*    qw1 = (float*)(w + 1572864);
  float*    qs  = (float*)(w + 1638400);
  float*    qe  = (float*)(w + 1638656);
  float*    att = (float*)(w + 1638912);
  float*    g   = (float*)(w + 1769984);
  unsigned* xrh = (unsigned*)(w + 1901056);
  unsigned short* ep = (unsigned short*)(w + 35455488);
  int*      mode = (int*)(w + 52232704);
  float* out = (float*)d_out;

  k_detect<<<dim3(1), dim3(256), 0, stream>>>(fact, mode);
  k_prep_w<<<dim3(256), dim3(256), 0, stream>>>(W1, Wr, Wh, Ur, Uh, mode, WK2, Urp, Uhp);
  k_prep_q<<<dim3(64), dim3(256), 0, stream>>>(q, W1, b1, Ws, bs, We, be, mode, qw1, qs, qe);
  k_main<<<dim3(2048), dim3(256), 0, stream>>>(fact, q, WK2, qw1, W2, b2v, br, bh, mode, att, xrh);
  k_softmax<<<dim3(64), dim3(512), 0, stream>>>(att, g);
  k_scan<<<dim3(16), dim3(256), 0, stream>>>(Urp, Uhp, xrh, g, ilen, ep);
  k_out<<<dim3(8192), dim3(256), 0, stream>>>(ep, Ws, We, qs, qe, mode, out);
}

// Round 10
// 1454.326 us; speedup vs baseline: 1.0441x; 1.0441x over previous
//
#include <hip/hip_runtime.h>
#include <cstddef>

// B=64, T=512, H=256. Float inputs fp32 (runtime-detected, bf16 fallback).
// Output fp32: [out_s (B*T), out_e (B*T)].
// ws layout (bytes): see kernel_launch.

static __device__ __forceinline__ float b2f(unsigned short u) {
  return __uint_as_float(((unsigned)u) << 16);
}
static __device__ __forceinline__ float blo(unsigned w) { return __uint_as_float(w << 16); }
static __device__ __forceinline__ float bhi(unsigned w) { return __uint_as_float(w & 0xffff0000u); }
static __device__ __forceinline__ unsigned short f2b(float f) {
  unsigned u = __float_as_uint(f);
  u += 0x7fffu + ((u >> 16) & 1u);  // RNE
  return (unsigned short)(u >> 16);
}
// adaptive input loads (md: 0=bf16 data, 1=fp32 data)
static __device__ __forceinline__ float ldf(const void* b, size_t i, int md) {
  return md ? ((const float*)b)[i] : b2f(((const unsigned short*)b)[i]);
}
static __device__ __forceinline__ unsigned short ldb(const void* b, size_t i, int md) {
  return md ? f2b(((const float*)b)[i]) : ((const unsigned short*)b)[i];
}

// MFMA fragment types (guide §3: bf16 16x16x32 -> 8 bf16 in/4 fp32 out)
typedef short bfrag __attribute__((ext_vector_type(8)));
typedef float f32x4 __attribute__((ext_vector_type(4)));

static __device__ __forceinline__ f32x4 sel4(int q, f32x4 a0, f32x4 a1, f32x4 a2, f32x4 a3) {
  return q == 0 ? a0 : (q == 1 ? a1 : (q == 2 ? a2 : a3));
}

// LDS-only workgroup barrier: no vmcnt(0) drain (global stores/loads stay
// in flight across it). Requires LLVM>=17 addrspace-fence builtin.
static __device__ __forceinline__ void sync_lds() {
  __builtin_amdgcn_fence(__ATOMIC_RELEASE, "workgroup", "local");
  __builtin_amdgcn_s_barrier();
  __builtin_amdgcn_fence(__ATOMIC_ACQUIRE, "workgroup", "local");
}

// ---------------- dtype detection ----------------
__global__ void k_detect(const void* __restrict__ fact, int* __restrict__ mode) {
  int tid = threadIdx.x;  // 256
  const unsigned short* u = (const unsigned short*)fact;
  float v = fabsf(b2f(u[2 * tid]));
  if (!(v == v)) v = 1e30f;
  for (int o = 32; o > 0; o >>= 1) v = fmaxf(v, __shfl_xor(v, o));
  __shared__ float red[4];
  int wave = tid >> 6, lane = tid & 63;
  if (lane == 0) red[wave] = v;
  __syncthreads();
  if (tid == 0) {
    float m = fmaxf(fmaxf(red[0], red[1]), fmaxf(red[2], red[3]));
    mode[0] = (m > 1e4f) ? 1 : 0;
  }
}

// ---------------- prep: combined weights + packed Ur/Uh ----------------
__global__ void k_prep_w(const void* __restrict__ W1,
                         const void* __restrict__ Wr,
                         const void* __restrict__ Wh,
                         const void* __restrict__ Ur,
                         const void* __restrict__ Uh,
                         const int* __restrict__ mode,
                         float* __restrict__ WK2,
                         unsigned* __restrict__ Urp,
                         unsigned* __restrict__ Uhp) {
  int md = *mode;
  int idx = blockIdx.x * 256 + threadIdx.x;  // 0..65535
  int i = idx >> 8, j = idx & 255;
  WK2[0 * 65536 + idx] = ldf(W1, idx, md);
  WK2[1 * 65536 + idx] = ldf(W1, (size_t)(768 + i) * 256 + j, md) + ldf(W1, (size_t)(1024 + i) * 256 + j, md);
  WK2[2 * 65536 + idx] = ldf(W1, (size_t)(1280 + i) * 256 + j, md) + ldf(W1, (size_t)(1536 + i) * 256 + j, md);
  WK2[3 * 65536 + idx] = ldf(Wr, idx, md);
  WK2[4 * 65536 + idx] = ldf(Wh, idx, md);
  if (i < 128) {
    Urp[idx] = (unsigned)ldb(Ur, (size_t)(2 * i) * 256 + j, md) |
               ((unsigned)ldb(Ur, (size_t)(2 * i + 1) * 256 + j, md) << 16);
    Uhp[idx] = (unsigned)ldb(Uh, (size_t)(2 * i) * 256 + j, md) |
               ((unsigned)ldb(Uh, (size_t)(2 * i + 1) * 256 + j, md) << 16);
  }
}

// ---------------- prep: q-dependent vectors ----------------
__global__ void k_prep_q(const void* __restrict__ q,
                         const void* __restrict__ W1,
                         const void* __restrict__ b1,
                         const void* __restrict__ Ws,
                         const void* __restrict__ bs,
                         const void* __restrict__ We,
                         const void* __restrict__ be,
                         const int* __restrict__ mode,
                         float* __restrict__ qw1,
                         float* __restrict__ qs,
                         float* __restrict__ qe) {
  __shared__ float qsh[256];
  __shared__ float reds[4], rede[4];
  int md = *mode;
  int b = blockIdx.x, tid = threadIdx.x;
  float qv = ldf(q, (size_t)b * 256 + tid, md);
  qsh[tid] = qv;
  __syncthreads();
  float acc = ldf(b1, tid, md);
  for (int i = 0; i < 256; ++i) {
    float w = ldf(W1, (size_t)(256 + i) * 256 + tid, md) + ldf(W1, (size_t)(512 + i) * 256 + tid, md);
    acc = fmaf(qsh[i], w, acc);
  }
  qw1[b * 256 + tid] = acc;
  float ps = qv * ldf(Ws, tid, md);
  float pe = qv * ldf(We, tid, md);
  for (int o = 32; o > 0; o >>= 1) { ps += __shfl_down(ps, o); pe += __shfl_down(pe, o); }
  int wave = tid >> 6, lane = tid & 63;
  if (lane == 0) { reds[wave] = ps; rede[wave] = pe; }
  __syncthreads();
  if (tid == 0) {
    qs[b] = ldf(bs, 0, md) + reds[0] + reds[1] + reds[2] + reds[3];
    qe[b] = ldf(be, 0, md) + rede[0] + rede[1] + rede[2] + rede[3];
  }
}

// ---------------- main GEMM: att pre-softmax + xr/xh ----------------
__launch_bounds__(256, 2)
__global__ void k_main(const void* __restrict__ fact,
                       const void* __restrict__ q,
                       const float* __restrict__ WK2,
                       const float* __restrict__ qw1,
                       const void* __restrict__ W2,
                       const void* __restrict__ b2v,
                       const void* __restrict__ br,
                       const void* __restrict__ bh,
                       const int* __restrict__ mode,
                       float* __restrict__ att,
                       unsigned* __restrict__ xrh) {
  __shared__ __align__(16) float sfT[256 * 20];
  __shared__ __align__(16) float sqT[256 * 20];
  __shared__ __align__(16) float saT[256 * 20];
  __shared__ float wsc[4 * 16];
  int md = *mode;
  int blk = blockIdx.x;
  int b = blk >> 5, t0 = (blk & 31) * 16;
  int tid = threadIdx.x;
  float qv = ldf(q, (size_t)b * 256 + tid, md);
  for (int r = 0; r < 16; ++r) {
    float f = ldf(fact, ((size_t)(b * 512 + t0 + r)) * 256 + tid, md);
    sfT[tid * 20 + r] = f;
    sqT[tid * 20 + r] = f * qv;
    saT[tid * 20 + r] = fabsf(f - qv);
  }
  __syncthreads();
  int jq = tid >> 2, rq = tid & 3;
  float u[4][4] = {{0}}, ar[4][4] = {{0}}, ah[4][4] = {{0}};
  const float* w0 = WK2 + jq * 4;
  const float* w1 = w0 + 65536;
  const float* w2 = w0 + 2 * 65536;
  const float* w3 = w0 + 3 * 65536;
  const float* w4 = w0 + 4 * 65536;
  for (int i = 0; i < 256; ++i) {
    float4 wf = *(const float4*)(w0 + i * 256);
    float4 wq = *(const float4*)(w1 + i * 256);
    float4 wa = *(const float4*)(w2 + i * 256);
    float4 wr4 = *(const float4*)(w3 + i * 256);
    float4 wh4 = *(const float4*)(w4 + i * 256);
    float4 s1 = *(const float4*)(sfT + i * 20 + rq * 4);
    float4 s2 = *(const float4*)(sqT + i * 20 + rq * 4);
    float4 s3 = *(const float4*)(saT + i * 20 + rq * 4);
    float s1a[4] = {s1.x, s1.y, s1.z, s1.w};
    float s2a[4] = {s2.x, s2.y, s2.z, s2.w};
    float s3a[4] = {s3.x, s3.y, s3.z, s3.w};
    float wfa[4] = {wf.x, wf.y, wf.z, wf.w};
    float wqa[4] = {wq.x, wq.y, wq.z, wq.w};
    float waa[4] = {wa.x, wa.y, wa.z, wa.w};
    float wra[4] = {wr4.x, wr4.y, wr4.z, wr4.w};
    float wha[4] = {wh4.x, wh4.y, wh4.z, wh4.w};
#pragma unroll
    for (int rr = 0; rr < 4; ++rr) {
#pragma unroll
      for (int jj = 0; jj < 4; ++jj) {
        u[rr][jj] = fmaf(s1a[rr], wfa[jj], u[rr][jj]);
        u[rr][jj] = fmaf(s2a[rr], wqa[jj], u[rr][jj]);
        u[rr][jj] = fmaf(s3a[rr], waa[jj], u[rr][jj]);
        ar[rr][jj] = fmaf(s1a[rr], wra[jj], ar[rr][jj]);
        ah[rr][jj] = fmaf(s1a[rr], wha[jj], ah[rr][jj]);
      }
    }
  }
  float qwv[4], w2v[4], brv[4], bhv[4];
#pragma unroll
  for (int jj = 0; jj < 4; ++jj) {
    int j = jq * 4 + jj;
    qwv[jj] = qw1[b * 256 + j];
    w2v[jj] = ldf(W2, j, md);
    brv[jj] = ldf(br, j, md);
    bhv[jj] = ldf(bh, j, md);
  }
  float patt[4];
#pragma unroll
  for (int rr = 0; rr < 4; ++rr) {
    float p = 0.f;
#pragma unroll
    for (int jj = 0; jj < 4; ++jj) {
      float hid = tanhf(u[rr][jj] + qwv[jj]);
      p = fmaf(hid, w2v[jj], p);
    }
    p += __shfl_down(p, 4);
    p += __shfl_down(p, 8);
    p += __shfl_down(p, 16);
    p += __shfl_down(p, 32);
    patt[rr] = p;
  }
  int wave = tid >> 6, lane = tid & 63;
  if (lane < 4) {
#pragma unroll
    for (int rr = 0; rr < 4; ++rr) wsc[wave * 16 + lane * 4 + rr] = patt[rr];
  }
  __syncthreads();
  if (tid < 16) {
    float s = wsc[tid] + wsc[16 + tid] + wsc[32 + tid] + wsc[48 + tid];
    att[b * 512 + t0 + tid] = s + ldf(b2v, 0, md);
  }
#pragma unroll
  for (int rr = 0; rr < 4; ++rr) {
    int t = t0 + rq * 4 + rr;
    unsigned vv[4];
#pragma unroll
    for (int jj = 0; jj < 4; ++jj) {
      unsigned lo = f2b(ar[rr][jj] + brv[jj]);
      unsigned hi = f2b(ah[rr][jj] + bhv[jj]);
      vv[jj] = lo | (hi << 16);
    }
    uint4 v;
    v.x = vv[0]; v.y = vv[1]; v.z = vv[2]; v.w = vv[3];
    *(uint4*)(xrh + ((size_t)(b * 512 + t)) * 256 + jq * 4) = v;
  }
}

// ---------------- softmax over T per batch ----------------
__global__ void k_softmax(const float* __restrict__ att, float* __restrict__ g) {
  __shared__ float red[8];
  int b = blockIdx.x, tid = threadIdx.x;  // 512 threads
  float v = att[b * 512 + tid];
  float m = v;
  for (int o = 32; o > 0; o >>= 1) m = fmaxf(m, __shfl_xor(m, o));
  int wave = tid >> 6, lane = tid & 63;
  if (lane == 0) red[wave] = m;
  __syncthreads();
  m = red[0];
#pragma unroll
  for (int w = 1; w < 8; ++w) m = fmaxf(m, red[w]);
  float e = __expf(v - m);
  float s = e;
  for (int o = 32; o > 0; o >>= 1) s += __shfl_xor(s, o);
  __syncthreads();
  if (lane == 0) red[wave] = s;
  __syncthreads();
  s = red[0] + red[1] + red[2] + red[3] + red[4] + red[5] + red[6] + red[7];
  g[b * 512 + tid] = e / s;
}

// ---------------- MFMA GRU scan: 4 batches per block, 16 blocks ----------------
// Same verified structure as round 9 (layouts unchanged), latency-trimmed:
//  - sync_lds(): LDS-only fences -> no vmcnt(0) drain at barriers; eb stores
//    and x prefetch loads stay in flight across steps.
//  - eb flushed at chunk START (reads previous chunk; ordered by phase-A
//    barrier against later eb writes).
//  - MFMA accumulator chains split 8 -> 2x4 (halved dependent latency).
//  - sigmoid/tanh via v_rcp_f32 (1 ulp) instead of IEEE division.
__launch_bounds__(256, 1)
__global__ void k_scan(const unsigned* __restrict__ Urp,
                       const unsigned* __restrict__ Uhp,
                       const unsigned* __restrict__ xrh,
                       const float* __restrict__ g,
                       const int* __restrict__ input_len,
                       unsigned short* __restrict__ ep) {
  __shared__ __align__(16) unsigned short hB[4 * 272];
  __shared__ __align__(16) unsigned short rhB[4 * 272];
  __shared__ float gsh[4 * 512];
  __shared__ __align__(16) unsigned xb[8 * 4 * 256];        // 32 KB
  __shared__ __align__(16) unsigned short eb[8 * 4 * 256];  // 16 KB
  int b0 = blockIdx.x * 4;
  int tid = threadIdx.x;
  int wv = tid >> 6, lane = tid & 63;
  int n16 = lane & 15, quad = lane >> 4;
  unsigned br_[4][8][4], bh_[4][8][4];
#pragma unroll
  for (int tile = 0; tile < 4; ++tile) {
    int col = wv * 64 + tile * 16 + n16;
#pragma unroll
    for (int kc = 0; kc < 8; ++kc) {
#pragma unroll
      for (int w = 0; w < 4; ++w) {
        int p = kc * 16 + quad * 4 + w;
        br_[tile][kc][w] = Urp[(size_t)p * 256 + col];
        bh_[tile][kc][w] = Uhp[(size_t)p * 256 + col];
      }
    }
  }
  for (int i = tid; i < 2048; i += 256)
    gsh[i] = g[(size_t)(b0 + (i >> 9)) * 512 + (i & 511)];
  for (int i = tid; i < 4 * 272; i += 256) { hB[i] = 0; rhB[i] = 0; }
  int len[4];
#pragma unroll
  for (int m = 0; m < 4; ++m) len[m] = input_len[b0 + m];
  float hm[4] = {0.f, 0.f, 0.f, 0.f};
  int cq = wv * 64 + quad * 16 + n16;
  uint4 pf[8];
#pragma unroll
  for (int k = 0; k < 8; ++k) {
    int i = tid + k * 256;
    int s = i >> 8, rem = i & 255, m = rem >> 6, jc = rem & 63;
    pf[k] = ((const uint4*)(xrh + ((size_t)(b0 + m) * 512 + s) * 256))[jc];
  }
  __syncthreads();
  unsigned xcc[4] = {0u, 0u, 0u, 0u};
  for (int t = 0; t < 512; ++t) {
    int tt = t & 7;
    if (tt == 0) {
      if (t != 0) {
        // flush previous chunk (steps t-8..t-1); stores never block barriers
#pragma unroll
        for (int k = 0; k < 4; ++k) {
          int i = tid + k * 256;
          uint4 ev = ((const uint4*)eb)[i];
          int sm = i >> 5, jc = i & 31;
          int s = sm >> 2, m = sm & 3;
          ((uint4*)(ep + ((size_t)(b0 + m) * 512 + (t - 8 + s)) * 256))[jc] = ev;
        }
      }
#pragma unroll
      for (int k = 0; k < 8; ++k) ((uint4*)xb)[tid + k * 256] = pf[k];
      sync_lds();
      if (t < 504) {
        int tb = (t >> 3) + 1;
#pragma unroll
        for (int k = 0; k < 8; ++k) {
          int i = tid + k * 256;
          int s = i >> 8, rem = i & 255, m = rem >> 6, jc = rem & 63;
          pf[k] = ((const uint4*)(xrh + ((size_t)(b0 + m) * 512 + tb * 8 + s) * 256))[jc];
        }
      }
    }
    // ---- phase A: rpre = h @ Ur (2x4 split chains) ----
#pragma unroll
    for (int m = 0; m < 4; ++m) xcc[m] = xb[((tt * 4 + m) << 8) + cq];
    f32x4 za = {0.f, 0.f, 0.f, 0.f};
    f32x4 lA0 = za, lA1 = za, lA2 = za, lA3 = za;
    f32x4 uA0 = za, uA1 = za, uA2 = za, uA3 = za;
#pragma unroll
    for (int kc = 0; kc < 4; ++kc) {
      uint4 av = *(const uint4*)((const char*)hB + (n16 & 3) * 544 + kc * 64 + quad * 16);
      bfrag af = __builtin_bit_cast(bfrag, av);
      uint4 av2 = *(const uint4*)((const char*)hB + (n16 & 3) * 544 + (kc + 4) * 64 + quad * 16);
      bfrag af2 = __builtin_bit_cast(bfrag, av2);
      uint4 b0v = {br_[0][kc][0], br_[0][kc][1], br_[0][kc][2], br_[0][kc][3]};
      uint4 b1v = {br_[1][kc][0], br_[1][kc][1], br_[1][kc][2], br_[1][kc][3]};
      uint4 b2v = {br_[2][kc][0], br_[2][kc][1], br_[2][kc][2], br_[2][kc][3]};
      uint4 b3v = {br_[3][kc][0], br_[3][kc][1], br_[3][kc][2], br_[3][kc][3]};
      uint4 c0v = {br_[0][kc + 4][0], br_[0][kc + 4][1], br_[0][kc + 4][2], br_[0][kc + 4][3]};
      uint4 c1v = {br_[1][kc + 4][0], br_[1][kc + 4][1], br_[1][kc + 4][2], br_[1][kc + 4][3]};
      uint4 c2v = {br_[2][kc + 4][0], br_[2][kc + 4][1], br_[2][kc + 4][2], br_[2][kc + 4][3]};
      uint4 c3v = {br_[3][kc + 4][0], br_[3][kc + 4][1], br_[3][kc + 4][2], br_[3][kc + 4][3]};
      lA0 = __builtin_amdgcn_mfma_f32_16x16x32_bf16(af, __builtin_bit_cast(bfrag, b0v), lA0, 0, 0, 0);
      lA1 = __builtin_amdgcn_mfma_f32_16x16x32_bf16(af, __builtin_bit_cast(bfrag, b1v), lA1, 0, 0, 0);
      lA2 = __builtin_amdgcn_mfma_f32_16x16x32_bf16(af, __builtin_bit_cast(bfrag, b2v), lA2, 0, 0, 0);
      lA3 = __builtin_amdgcn_mfma_f32_16x16x32_bf16(af, __builtin_bit_cast(bfrag, b3v), lA3, 0, 0, 0);
      uA0 = __builtin_amdgcn_mfma_f32_16x16x32_bf16(af2, __builtin_bit_cast(bfrag, c0v), uA0, 0, 0, 0);
      uA1 = __builtin_amdgcn_mfma_f32_16x16x32_bf16(af2, __builtin_bit_cast(bfrag, c1v), uA1, 0, 0, 0);
      uA2 = __builtin_amdgcn_mfma_f32_16x16x32_bf16(af2, __builtin_bit_cast(bfrag, c2v), uA2, 0, 0, 0);
      uA3 = __builtin_amdgcn_mfma_f32_16x16x32_bf16(af2, __builtin_bit_cast(bfrag, c3v), uA3, 0, 0, 0);
    }
    {
      f32x4 my = sel4(quad, lA0 + uA0, lA1 + uA1, lA2 + uA2, lA3 + uA3);
#pragma unroll
      for (int m = 0; m < 4; ++m) {
        float e = __expf(-(my[m] + blo(xcc[m])));
        float r = __builtin_amdgcn_rcpf(1.f + e);
        rhB[m * 272 + cq] = f2b(r * hm[m]);
      }
    }
    sync_lds();
    // ---- phase B: hpre = (r*h) @ Uh ----
    f32x4 lB0 = za, lB1 = za, lB2 = za, lB3 = za;
    f32x4 uB0 = za, uB1 = za, uB2 = za, uB3 = za;
#pragma unroll
    for (int kc = 0; kc < 4; ++kc) {
      uint4 av = *(const uint4*)((const char*)rhB + (n16 & 3) * 544 + kc * 64 + quad * 16);
      bfrag af = __builtin_bit_cast(bfrag, av);
      uint4 av2 = *(const uint4*)((const char*)rhB + (n16 & 3) * 544 + (kc + 4) * 64 + quad * 16);
      bfrag af2 = __builtin_bit_cast(bfrag, av2);
      uint4 b0v = {bh_[0][kc][0], bh_[0][kc][1], bh_[0][kc][2], bh_[0][kc][3]};
      uint4 b1v = {bh_[1][kc][0], bh_[1][kc][1], bh_[1][kc][2], bh_[1][kc][3]};
      uint4 b2v = {bh_[2][kc][0], bh_[2][kc][1], bh_[2][kc][2], bh_[2][kc][3]};
      uint4 b3v = {bh_[3][kc][0], bh_[3][kc][1], bh_[3][kc][2], bh_[3][kc][3]};
      uint4 c0v = {bh_[0][kc + 4][0], bh_[0][kc + 4][1], bh_[0][kc + 4][2], bh_[0][kc + 4][3]};
      uint4 c1v = {bh_[1][kc + 4][0], bh_[1][kc + 4][1], bh_[1][kc + 4][2], bh_[1][kc + 4][3]};
      uint4 c2v = {bh_[2][kc + 4][0], bh_[2][kc + 4][1], bh_[2][kc + 4][2], bh_[2][kc + 4][3]};
      uint4 c3v = {bh_[3][kc + 4][0], bh_[3][kc + 4][1], bh_[3][kc + 4][2], bh_[3][kc + 4][3]};
      lB0 = __builtin_amdgcn_mfma_f32_16x16x32_bf16(af, __builtin_bit_cast(bfrag, b0v), lB0, 0, 0, 0);
      lB1 = __builtin_amdgcn_mfma_f32_16x16x32_bf16(af, __builtin_bit_cast(bfrag, b1v), lB1, 0, 0, 0);
      lB2 = __builtin_amdgcn_mfma_f32_16x16x32_bf16(af, __builtin_bit_cast(bfrag, b2v), lB2, 0, 0, 0);
      lB3 = __builtin_amdgcn_mfma_f32_16x16x32_bf16(af, __builtin_bit_cast(bfrag, b3v), lB3, 0, 0, 0);
      uB0 = __builtin_amdgcn_mfma_f32_16x16x32_bf16(af2, __builtin_bit_cast(bfrag, c0v), uB0, 0, 0, 0);
      uB1 = __builtin_amdgcn_mfma_f32_16x16x32_bf16(af2, __builtin_bit_cast(bfrag, c1v), uB1, 0, 0, 0);
      uB2 = __builtin_amdgcn_mfma_f32_16x16x32_bf16(af2, __builtin_bit_cast(bfrag, c2v), uB2, 0, 0, 0);
      uB3 = __builtin_amdgcn_mfma_f32_16x16x32_bf16(af2, __builtin_bit_cast(bfrag, c3v), uB3, 0, 0, 0);
    }
    {
      f32x4 myc = sel4(quad, lB0 + uB0, lB1 + uB1, lB2 + uB2, lB3 + uB3);
#pragma unroll
      for (int m = 0; m < 4; ++m) {
        float xcl = fminf(fmaxf(myc[m] + bhi(xcc[m]), -15.f), 15.f);
        float exv = __expf(2.f * xcl);
        float hc = 1.f - 2.f * __builtin_amdgcn_rcpf(exv + 1.f);
        float gt = gsh[m * 512 + t];
        bool valid = t < len[m];
        float hn = hm[m] + gt * (hc - hm[m]);
        hm[m] = valid ? hn : hm[m];
        hB[m * 272 + cq] = f2b(hm[m]);
        eb[((tt * 4 + m) << 8) + cq] = f2b(valid ? hm[m] : 0.f);
      }
    }
    sync_lds();
  }
  // final flush: steps 504..511
#pragma unroll
  for (int k = 0; k < 4; ++k) {
    int i = tid + k * 256;
    uint4 ev = ((const uint4*)eb)[i];
    int sm = i >> 5, jc = i & 31;
    int s = sm >> 2, m = sm & 3;
    ((uint4*)(ep + ((size_t)(b0 + m) * 512 + (504 + s)) * 256))[jc] = ev;
  }
}

// ---------------- final dense: out_s/out_e (fp32 output) ----------------
__global__ void k_out(const unsigned short* __restrict__ ep,
                      const void* __restrict__ Ws,
                      const void* __restrict__ We,
                      const float* __restrict__ qs,
                      const float* __restrict__ qe,
                      const int* __restrict__ mode,
                      float* __restrict__ out) {
  int md = *mode;
  int tid = threadIdx.x;
  int wave = tid >> 6, lane = tid & 63;
  int row = blockIdx.x * 4 + wave;  // (b,t) flat, 0..32767
  const unsigned short* er = ep + (size_t)row * 256 + lane * 4;
  float f0 = b2f(er[0]), f1 = b2f(er[1]), f2 = b2f(er[2]), f3 = b2f(er[3]);
  int n = 256 + lane * 4;
  float s = f0 * ldf(Ws, n, md) + f1 * ldf(Ws, n + 1, md) + f2 * ldf(Ws, n + 2, md) + f3 * ldf(Ws, n + 3, md);
  float e = f0 * ldf(We, n, md) + f1 * ldf(We, n + 1, md) + f2 * ldf(We, n + 2, md) + f3 * ldf(We, n + 3, md);
  for (int o = 32; o > 0; o >>= 1) { s += __shfl_down(s, o); e += __shfl_down(e, o); }
  if (lane == 0) {
    int b = row >> 9;
    out[row] = tanhf(qs[b] + s);
    out[32768 + row] = tanhf(qe[b] + e);
  }
}

extern "C" void kernel_launch(void* const* d_in, const int* in_sizes, int n_in,
                              void* d_out, int out_size, void* d_ws, size_t ws_size,
                              hipStream_t stream) {
  const void* q    = d_in[0];
  const void* fact = d_in[1];
  const int* ilen  = (const int*)d_in[2];
  const void* W1   = d_in[3];
  const void* b1   = d_in[4];
  const void* W2   = d_in[5];
  const void* b2v  = d_in[6];
  const void* Wr   = d_in[7];
  const void* Ur   = d_in[8];
  const void* br   = d_in[9];
  const void* Wh   = d_in[10];
  const void* Uh   = d_in[11];
  const void* bh   = d_in[12];
  const void* Ws   = d_in[13];
  const void* bs   = d_in[14];
  const void* We   = d_in[15];
  const void* be   = d_in[16];

  char* w = (char*)d_ws;
  float*    WK2 = (float*)(w);
  unsigned* Urp = (unsigned*)(w + 1310720);
  unsigned* Uhp = (unsigned*)(w + 1441792);
  float*    qw1 = (float*)(w + 1572864);
  float*    qs  = (float*)(w + 1638400);
  float*    qe  = (float*)(w + 1638656);
  float*    att = (float*)(w + 1638912);
  float*    g   = (float*)(w + 1769984);
  unsigned* xrh = (unsigned*)(w + 1901056);
  unsigned short* ep = (unsigned short*)(w + 35455488);
  int*      mode = (int*)(w + 52232704);
  float* out = (float*)d_out;

  k_detect<<<dim3(1), dim3(256), 0, stream>>>(fact, mode);
  k_prep_w<<<dim3(256), dim3(256), 0, stream>>>(W1, Wr, Wh, Ur, Uh, mode, WK2, Urp, Uhp);
  k_prep_q<<<dim3(64), dim3(256), 0, stream>>>(q, W1, b1, Ws, bs, We, be, mode, qw1, qs, qe);
  k_main<<<dim3(2048), dim3(256), 0, stream>>>(fact, q, WK2, qw1, W2, b2v, br, bh, mode, att, xrh);
  k_softmax<<<dim3(64), dim3(512), 0, stream>>>(att, g);
  k_scan<<<dim3(16), dim3(256), 0, stream>>>(Urp, Uhp, xrh, g, ilen, ep);
  k_out<<<dim3(8192), dim3(256), 0, stream>>>(ep, Ws, We, qs, qe, mode, out);
}

// Round 11
// 1149.880 us; speedup vs baseline: 1.3206x; 1.2648x over previous
//
#include <hip/hip_runtime.h>
#include <cstddef>

// B=64, T=512, H=256. Float inputs fp32 (runtime-detected, bf16 fallback).
// Output fp32: [out_s (B*T), out_e (B*T)].
// ws layout (bytes):
//   0        W5q   640*256 u32 bf16-pair B-frags, uint4-grouped:
//                  idx = ((p>>2)*256+col)*4+(p&3); p: 0..127 W1f, 128..255
//                  W1fq+W1fm, 256..383 W1afq+afm, 384..511 Wr, 512..639 Wh
//   1310720  Urp   128*256 u32  (bf16 pairs along i)
//   1441792  Uhp   128*256 u32
//   1572864  qw1   64*256 f32
//   1638400  qs    64 f32
//   1638656  qe    64 f32
//   1638912  att   64*512 f32
//   1769984  g     64*512 f32
//   1901056  xrh   64*512*256 u32
//   35455488 ep    64*512*256 bf16
//   52232704 mode  int

static __device__ __forceinline__ float b2f(unsigned short u) {
  return __uint_as_float(((unsigned)u) << 16);
}
static __device__ __forceinline__ float blo(unsigned w) { return __uint_as_float(w << 16); }
static __device__ __forceinline__ float bhi(unsigned w) { return __uint_as_float(w & 0xffff0000u); }
static __device__ __forceinline__ unsigned short f2b(float f) {
  unsigned u = __float_as_uint(f);
  u += 0x7fffu + ((u >> 16) & 1u);  // RNE
  return (unsigned short)(u >> 16);
}
static __device__ __forceinline__ float ldf(const void* b, size_t i, int md) {
  return md ? ((const float*)b)[i] : b2f(((const unsigned short*)b)[i]);
}
static __device__ __forceinline__ unsigned short ldb(const void* b, size_t i, int md) {
  return md ? f2b(((const float*)b)[i]) : ((const unsigned short*)b)[i];
}

typedef short bfrag __attribute__((ext_vector_type(8)));
typedef float f32x4 __attribute__((ext_vector_type(4)));

static __device__ __forceinline__ f32x4 sel4(int q, f32x4 a0, f32x4 a1, f32x4 a2, f32x4 a3) {
  return q == 0 ? a0 : (q == 1 ? a1 : (q == 2 ? a2 : a3));
}
template <int CTRL>
static __device__ __forceinline__ float dpp_add(float x) {
  int v = __builtin_amdgcn_update_dpp(0, __float_as_int(x), CTRL, 0xF, 0xF, true);
  return x + __int_as_float(v);
}
static __device__ __forceinline__ float red16(float x) {
  x = dpp_add<0xB1>(x);
  x = dpp_add<0x4E>(x);
  x = dpp_add<0x141>(x);
  x = dpp_add<0x140>(x);
  return x;
}
static __device__ __forceinline__ void sync_lds() {
  __builtin_amdgcn_fence(__ATOMIC_RELEASE, "workgroup", "local");
  __builtin_amdgcn_s_barrier();
  __builtin_amdgcn_fence(__ATOMIC_ACQUIRE, "workgroup", "local");
}
static __device__ __forceinline__ float fast_tanh(float x) {
  float xc = fminf(fmaxf(x, -15.f), 15.f);
  return 1.f - 2.f * __builtin_amdgcn_rcpf(__expf(2.f * xc) + 1.f);
}

// ---------------- dtype detection ----------------
__global__ void k_detect(const void* __restrict__ fact, int* __restrict__ mode) {
  int tid = threadIdx.x;  // 256
  const unsigned short* u = (const unsigned short*)fact;
  float v = fabsf(b2f(u[2 * tid]));
  if (!(v == v)) v = 1e30f;
  for (int o = 32; o > 0; o >>= 1) v = fmaxf(v, __shfl_xor(v, o));
  __shared__ float red[4];
  int wave = tid >> 6, lane = tid & 63;
  if (lane == 0) red[wave] = v;
  __syncthreads();
  if (tid == 0) {
    float m = fmaxf(fmaxf(red[0], red[1]), fmaxf(red[2], red[3]));
    mode[0] = (m > 1e4f) ? 1 : 0;
  }
}

// ---------------- prep: packed bf16 weights ----------------
// 128 blocks x 256: i in 0..127 (pair row), j in 0..255 (col)
__global__ void k_prep_w(const void* __restrict__ W1,
                         const void* __restrict__ Wr,
                         const void* __restrict__ Wh,
                         const void* __restrict__ Ur,
                         const void* __restrict__ Uh,
                         const int* __restrict__ mode,
                         unsigned* __restrict__ W5q,
                         unsigned* __restrict__ Urp,
                         unsigned* __restrict__ Uhp) {
  int md = *mode;
  int idx = blockIdx.x * 256 + threadIdx.x;  // 0..32767
  int i = idx >> 8, j = idx & 255;
  Urp[idx] = (unsigned)ldb(Ur, (size_t)(2 * i) * 256 + j, md) |
             ((unsigned)ldb(Ur, (size_t)(2 * i + 1) * 256 + j, md) << 16);
  Uhp[idx] = (unsigned)ldb(Uh, (size_t)(2 * i) * 256 + j, md) |
             ((unsigned)ldb(Uh, (size_t)(2 * i + 1) * 256 + j, md) << 16);
  // W5q: idx4(p) = ((p>>2)*256 + j)*4 + (p&3)
  float v0, v1;
  int p;
  p = i;  // stream 0: W1 rows [0,256) (f)
  v0 = ldf(W1, (size_t)(2 * i) * 256 + j, md);
  v1 = ldf(W1, (size_t)(2 * i + 1) * 256 + j, md);
  W5q[(((p >> 2) * 256 + j) << 2) + (p & 3)] = (unsigned)f2b(v0) | ((unsigned)f2b(v1) << 16);
  p = 128 + i;  // stream 1: f*q combined
  v0 = ldf(W1, (size_t)(768 + 2 * i) * 256 + j, md) + ldf(W1, (size_t)(1024 + 2 * i) * 256 + j, md);
  v1 = ldf(W1, (size_t)(769 + 2 * i) * 256 + j, md) + ldf(W1, (size_t)(1025 + 2 * i) * 256 + j, md);
  W5q[(((p >> 2) * 256 + j) << 2) + (p & 3)] = (unsigned)f2b(v0) | ((unsigned)f2b(v1) << 16);
  p = 256 + i;  // stream 2: |f-q| combined
  v0 = ldf(W1, (size_t)(1280 + 2 * i) * 256 + j, md) + ldf(W1, (size_t)(1536 + 2 * i) * 256 + j, md);
  v1 = ldf(W1, (size_t)(1281 + 2 * i) * 256 + j, md) + ldf(W1, (size_t)(1537 + 2 * i) * 256 + j, md);
  W5q[(((p >> 2) * 256 + j) << 2) + (p & 3)] = (unsigned)f2b(v0) | ((unsigned)f2b(v1) << 16);
  p = 384 + i;  // stream 3: Wr
  v0 = ldf(Wr, (size_t)(2 * i) * 256 + j, md);
  v1 = ldf(Wr, (size_t)(2 * i + 1) * 256 + j, md);
  W5q[(((p >> 2) * 256 + j) << 2) + (p & 3)] = (unsigned)f2b(v0) | ((unsigned)f2b(v1) << 16);
  p = 512 + i;  // stream 4: Wh
  v0 = ldf(Wh, (size_t)(2 * i) * 256 + j, md);
  v1 = ldf(Wh, (size_t)(2 * i + 1) * 256 + j, md);
  W5q[(((p >> 2) * 256 + j) << 2) + (p & 3)] = (unsigned)f2b(v0) | ((unsigned)f2b(v1) << 16);
}

// ---------------- prep: q-dependent vectors ----------------
__global__ void k_prep_q(const void* __restrict__ q,
                         const void* __restrict__ W1,
                         const void* __restrict__ b1,
                         const void* __restrict__ Ws,
                         const void* __restrict__ bs,
                         const void* __restrict__ We,
                         const void* __restrict__ be,
                         const int* __restrict__ mode,
                         float* __restrict__ qw1,
                         float* __restrict__ qs,
                         float* __restrict__ qe) {
  __shared__ float qsh[256];
  __shared__ float reds[4], rede[4];
  int md = *mode;
  int b = blockIdx.x, tid = threadIdx.x;
  float qv = ldf(q, (size_t)b * 256 + tid, md);
  qsh[tid] = qv;
  __syncthreads();
  float acc = ldf(b1, tid, md);
  for (int i = 0; i < 256; ++i) {
    float w = ldf(W1, (size_t)(256 + i) * 256 + tid, md) + ldf(W1, (size_t)(512 + i) * 256 + tid, md);
    acc = fmaf(qsh[i], w, acc);
  }
  qw1[b * 256 + tid] = acc;
  float ps = qv * ldf(Ws, tid, md);
  float pe = qv * ldf(We, tid, md);
  for (int o = 32; o > 0; o >>= 1) { ps += __shfl_down(ps, o); pe += __shfl_down(pe, o); }
  int wave = tid >> 6, lane = tid & 63;
  if (lane == 0) { reds[wave] = ps; rede[wave] = pe; }
  __syncthreads();
  if (tid == 0) {
    qs[b] = ldf(bs, 0, md) + reds[0] + reds[1] + reds[2] + reds[3];
    qe[b] = ldf(be, 0, md) + rede[0] + rede[1] + rede[2] + rede[3];
  }
}

// ---------------- main GEMM via MFMA: att pre-softmax + xr/xh ----------------
// 2048 blocks = 64 b x 32 t-tiles of 16 rows. 256 thr = 4 waves; wave wv owns
// cols [wv*64, wv*64+64) as 4 N-tiles. A = 16 rows x 768 bf16 feats in LDS
// (row stride 388 dw == 4 mod 32 -> uniform bank touches). kc 0..7: u+ar+ah;
// kc 8..23: u only. B-frags: single coalesced uint4 load from W5q.
__launch_bounds__(256, 2)
__global__ void k_main(const void* __restrict__ fact,
                       const void* __restrict__ q,
                       const unsigned* __restrict__ W5q,
                       const float* __restrict__ qw1,
                       const void* __restrict__ W2,
                       const void* __restrict__ b2v,
                       const void* __restrict__ br,
                       const void* __restrict__ bh,
                       const int* __restrict__ mode,
                       float* __restrict__ att,
                       unsigned* __restrict__ xrh) {
  __shared__ __align__(16) unsigned short A[16 * 776];  // 776 u16 = 388 dw rows
  __shared__ float wsc[64];
  int md = *mode;
  int blk = blockIdx.x;
  int b = blk >> 5, t0 = (blk & 31) * 16;
  int tid = threadIdx.x;
  {
    float qv = ldf(q, (size_t)b * 256 + tid, md);
    for (int r = 0; r < 16; ++r) {
      float f = ldf(fact, ((size_t)(b * 512 + t0 + r)) * 256 + tid, md);
      A[r * 776 + tid] = f2b(f);
      A[r * 776 + 256 + tid] = f2b(f * qv);
      A[r * 776 + 512 + tid] = f2b(fabsf(f - qv));
    }
  }
  __syncthreads();
  int wv = tid >> 6, lane = tid & 63;
  int n16 = lane & 15, quad = lane >> 4;
  int colb = wv * 64 + n16;
  const uint4* W4 = (const uint4*)W5q;  // uint4 idx = pgroup*256 + col
  f32x4 z = {0.f, 0.f, 0.f, 0.f};
  f32x4 u[4] = {z, z, z, z}, ar[4] = {z, z, z, z}, ah[4] = {z, z, z, z};
  // kc 0..7: f-region -> u (pgrp kc*4+quad), ar (96+kc*4+quad), ah (128+..)
#pragma unroll
  for (int kc = 0; kc < 8; ++kc) {
    uint4 av = *(const uint4*)((const char*)A + n16 * 1552 + kc * 64 + quad * 16);
    bfrag af = __builtin_bit_cast(bfrag, av);
    int pg = kc * 4 + quad;
#pragma unroll
    for (int tile = 0; tile < 4; ++tile) {
      int col = colb + tile * 16;
      uint4 bu = W4[(size_t)pg * 256 + col];
      uint4 bw = W4[(size_t)(96 + pg) * 256 + col];
      uint4 bv = W4[(size_t)(128 + pg) * 256 + col];
      u[tile] = __builtin_amdgcn_mfma_f32_16x16x32_bf16(af, __builtin_bit_cast(bfrag, bu), u[tile], 0, 0, 0);
      ar[tile] = __builtin_amdgcn_mfma_f32_16x16x32_bf16(af, __builtin_bit_cast(bfrag, bw), ar[tile], 0, 0, 0);
      ah[tile] = __builtin_amdgcn_mfma_f32_16x16x32_bf16(af, __builtin_bit_cast(bfrag, bv), ah[tile], 0, 0, 0);
    }
  }
  // kc 8..23: fq/fa regions -> u only
#pragma unroll
  for (int kc = 8; kc < 24; ++kc) {
    uint4 av = *(const uint4*)((const char*)A + n16 * 1552 + kc * 64 + quad * 16);
    bfrag af = __builtin_bit_cast(bfrag, av);
    int pg = kc * 4 + quad;
#pragma unroll
    for (int tile = 0; tile < 4; ++tile) {
      int col = colb + tile * 16;
      uint4 bu = W4[(size_t)pg * 256 + col];
      u[tile] = __builtin_amdgcn_mfma_f32_16x16x32_bf16(af, __builtin_bit_cast(bfrag, bu), u[tile], 0, 0, 0);
    }
  }
  float qwv[4], w2v[4], brv[4], bhv[4];
#pragma unroll
  for (int tile = 0; tile < 4; ++tile) {
    int col = colb + tile * 16;
    qwv[tile] = qw1[b * 256 + col];
    w2v[tile] = ldf(W2, col, md);
    brv[tile] = ldf(br, col, md);
    bhv[tile] = ldf(bh, col, md);
  }
  // att: per row (quad*4+reg) reduce tanh(u+qw1)*W2 over cols
  float ps[4];
#pragma unroll
  for (int reg = 0; reg < 4; ++reg) {
    float p = 0.f;
#pragma unroll
    for (int tile = 0; tile < 4; ++tile) {
      float hid = fast_tanh(u[tile][reg] + qwv[tile]);
      p = fmaf(hid, w2v[tile], p);
    }
    ps[reg] = red16(p);
  }
  if (n16 == 0) {
#pragma unroll
    for (int reg = 0; reg < 4; ++reg) wsc[wv * 16 + quad * 4 + reg] = ps[reg];
  }
  __syncthreads();
  if (tid < 16) {
    att[b * 512 + t0 + tid] =
        wsc[tid] + wsc[16 + tid] + wsc[32 + tid] + wsc[48 + tid] + ldf(b2v, 0, md);
  }
  // xrh: packed bf16(xr+br)|bf16(xh+bh)<<16, row t = t0+quad*4+reg, col
#pragma unroll
  for (int tile = 0; tile < 4; ++tile) {
    int col = colb + tile * 16;
#pragma unroll
    for (int reg = 0; reg < 4; ++reg) {
      int t = t0 + quad * 4 + reg;
      unsigned v = (unsigned)f2b(ar[tile][reg] + brv[tile]) |
                   ((unsigned)f2b(ah[tile][reg] + bhv[tile]) << 16);
      xrh[((size_t)(b * 512 + t)) * 256 + col] = v;
    }
  }
}

// ---------------- softmax over T per batch ----------------
__global__ void k_softmax(const float* __restrict__ att, float* __restrict__ g) {
  __shared__ float red[8];
  int b = blockIdx.x, tid = threadIdx.x;  // 512 threads
  float v = att[b * 512 + tid];
  float m = v;
  for (int o = 32; o > 0; o >>= 1) m = fmaxf(m, __shfl_xor(m, o));
  int wave = tid >> 6, lane = tid & 63;
  if (lane == 0) red[wave] = m;
  __syncthreads();
  m = red[0];
#pragma unroll
  for (int w = 1; w < 8; ++w) m = fmaxf(m, red[w]);
  float e = __expf(v - m);
  float s = e;
  for (int o = 32; o > 0; o >>= 1) s += __shfl_xor(s, o);
  __syncthreads();
  if (lane == 0) red[wave] = s;
  __syncthreads();
  s = red[0] + red[1] + red[2] + red[3] + red[4] + red[5] + red[6] + red[7];
  g[b * 512 + tid] = e / s;
}

// ---------------- MFMA GRU scan (round-10 structure, unchanged) ----------------
__launch_bounds__(256, 1)
__global__ void k_scan(const unsigned* __restrict__ Urp,
                       const unsigned* __restrict__ Uhp,
                       const unsigned* __restrict__ xrh,
                       const float* __restrict__ g,
                       const int* __restrict__ input_len,
                       unsigned short* __restrict__ ep) {
  __shared__ __align__(16) unsigned short hB[4 * 272];
  __shared__ __align__(16) unsigned short rhB[4 * 272];
  __shared__ float gsh[4 * 512];
  __shared__ __align__(16) unsigned xb[8 * 4 * 256];
  __shared__ __align__(16) unsigned short eb[8 * 4 * 256];
  int b0 = blockIdx.x * 4;
  int tid = threadIdx.x;
  int wv = tid >> 6, lane = tid & 63;
  int n16 = lane & 15, quad = lane >> 4;
  unsigned br_[4][8][4], bh_[4][8][4];
#pragma unroll
  for (int tile = 0; tile < 4; ++tile) {
    int col = wv * 64 + tile * 16 + n16;
#pragma unroll
    for (int kc = 0; kc < 8; ++kc) {
#pragma unroll
      for (int w = 0; w < 4; ++w) {
        int p = kc * 16 + quad * 4 + w;
        br_[tile][kc][w] = Urp[(size_t)p * 256 + col];
        bh_[tile][kc][w] = Uhp[(size_t)p * 256 + col];
      }
    }
  }
  for (int i = tid; i < 2048; i += 256)
    gsh[i] = g[(size_t)(b0 + (i >> 9)) * 512 + (i & 511)];
  for (int i = tid; i < 4 * 272; i += 256) { hB[i] = 0; rhB[i] = 0; }
  int len[4];
#pragma unroll
  for (int m = 0; m < 4; ++m) len[m] = input_len[b0 + m];
  float hm[4] = {0.f, 0.f, 0.f, 0.f};
  int cq = wv * 64 + quad * 16 + n16;
  uint4 pf[8];
#pragma unroll
  for (int k = 0; k < 8; ++k) {
    int i = tid + k * 256;
    int s = i >> 8, rem = i & 255, m = rem >> 6, jc = rem & 63;
    pf[k] = ((const uint4*)(xrh + ((size_t)(b0 + m) * 512 + s) * 256))[jc];
  }
  __syncthreads();
  unsigned xcc[4] = {0u, 0u, 0u, 0u};
  for (int t = 0; t < 512; ++t) {
    int tt = t & 7;
    if (tt == 0) {
      if (t != 0) {
#pragma unroll
        for (int k = 0; k < 4; ++k) {
          int i = tid + k * 256;
          uint4 ev = ((const uint4*)eb)[i];
          int sm = i >> 5, jc = i & 31;
          int s = sm >> 2, m = sm & 3;
          ((uint4*)(ep + ((size_t)(b0 + m) * 512 + (t - 8 + s)) * 256))[jc] = ev;
        }
      }
#pragma unroll
      for (int k = 0; k < 8; ++k) ((uint4*)xb)[tid + k * 256] = pf[k];
      sync_lds();
      if (t < 504) {
        int tb = (t >> 3) + 1;
#pragma unroll
        for (int k = 0; k < 8; ++k) {
          int i = tid + k * 256;
          int s = i >> 8, rem = i & 255, m = rem >> 6, jc = rem & 63;
          pf[k] = ((const uint4*)(xrh + ((size_t)(b0 + m) * 512 + tb * 8 + s) * 256))[jc];
        }
      }
    }
#pragma unroll
    for (int m = 0; m < 4; ++m) xcc[m] = xb[((tt * 4 + m) << 8) + cq];
    f32x4 za = {0.f, 0.f, 0.f, 0.f};
    f32x4 lA0 = za, lA1 = za, lA2 = za, lA3 = za;
    f32x4 uA0 = za, uA1 = za, uA2 = za, uA3 = za;
#pragma unroll
    for (int kc = 0; kc < 4; ++kc) {
      uint4 av = *(const uint4*)((const char*)hB + (n16 & 3) * 544 + kc * 64 + quad * 16);
      bfrag af = __builtin_bit_cast(bfrag, av);
      uint4 av2 = *(const uint4*)((const char*)hB + (n16 & 3) * 544 + (kc + 4) * 64 + quad * 16);
      bfrag af2 = __builtin_bit_cast(bfrag, av2);
      uint4 b0v = {br_[0][kc][0], br_[0][kc][1], br_[0][kc][2], br_[0][kc][3]};
      uint4 b1v = {br_[1][kc][0], br_[1][kc][1], br_[1][kc][2], br_[1][kc][3]};
      uint4 b2v = {br_[2][kc][0], br_[2][kc][1], br_[2][kc][2], br_[2][kc][3]};
      uint4 b3v = {br_[3][kc][0], br_[3][kc][1], br_[3][kc][2], br_[3][kc][3]};
      uint4 c0v = {br_[0][kc + 4][0], br_[0][kc + 4][1], br_[0][kc + 4][2], br_[0][kc + 4][3]};
      uint4 c1v = {br_[1][kc + 4][0], br_[1][kc + 4][1], br_[1][kc + 4][2], br_[1][kc + 4][3]};
      uint4 c2v = {br_[2][kc + 4][0], br_[2][kc + 4][1], br_[2][kc + 4][2], br_[2][kc + 4][3]};
      uint4 c3v = {br_[3][kc + 4][0], br_[3][kc + 4][1], br_[3][kc + 4][2], br_[3][kc + 4][3]};
      lA0 = __builtin_amdgcn_mfma_f32_16x16x32_bf16(af, __builtin_bit_cast(bfrag, b0v), lA0, 0, 0, 0);
      lA1 = __builtin_amdgcn_mfma_f32_16x16x32_bf16(af, __builtin_bit_cast(bfrag, b1v), lA1, 0, 0, 0);
      lA2 = __builtin_amdgcn_mfma_f32_16x16x32_bf16(af, __builtin_bit_cast(bfrag, b2v), lA2, 0, 0, 0);
      lA3 = __builtin_amdgcn_mfma_f32_16x16x32_bf16(af, __builtin_bit_cast(bfrag, b3v), lA3, 0, 0, 0);
      uA0 = __builtin_amdgcn_mfma_f32_16x16x32_bf16(af2, __builtin_bit_cast(bfrag, c0v), uA0, 0, 0, 0);
      uA1 = __builtin_amdgcn_mfma_f32_16x16x32_bf16(af2, __builtin_bit_cast(bfrag, c1v), uA1, 0, 0, 0);
      uA2 = __builtin_amdgcn_mfma_f32_16x16x32_bf16(af2, __builtin_bit_cast(bfrag, c2v), uA2, 0, 0, 0);
      uA3 = __builtin_amdgcn_mfma_f32_16x16x32_bf16(af2, __builtin_bit_cast(bfrag, c3v), uA3, 0, 0, 0);
    }
    {
      f32x4 my = sel4(quad, lA0 + uA0, lA1 + uA1, lA2 + uA2, lA3 + uA3);
#pragma unroll
      for (int m = 0; m < 4; ++m) {
        float e = __expf(-(my[m] + blo(xcc[m])));
        float r = __builtin_amdgcn_rcpf(1.f + e);
        rhB[m * 272 + cq] = f2b(r * hm[m]);
      }
    }
    sync_lds();
    f32x4 za2 = {0.f, 0.f, 0.f, 0.f};
    f32x4 lB0 = za2, lB1 = za2, lB2 = za2, lB3 = za2;
    f32x4 uB0 = za2, uB1 = za2, uB2 = za2, uB3 = za2;
#pragma unroll
    for (int kc = 0; kc < 4; ++kc) {
      uint4 av = *(const uint4*)((const char*)rhB + (n16 & 3) * 544 + kc * 64 + quad * 16);
      bfrag af = __builtin_bit_cast(bfrag, av);
      uint4 av2 = *(const uint4*)((const char*)rhB + (n16 & 3) * 544 + (kc + 4) * 64 + quad * 16);
      bfrag af2 = __builtin_bit_cast(bfrag, av2);
      uint4 b0v = {bh_[0][kc][0], bh_[0][kc][1], bh_[0][kc][2], bh_[0][kc][3]};
      uint4 b1v = {bh_[1][kc][0], bh_[1][kc][1], bh_[1][kc][2], bh_[1][kc][3]};
      uint4 b2v = {bh_[2][kc][0], bh_[2][kc][1], bh_[2][kc][2], bh_[2][kc][3]};
      uint4 b3v = {bh_[3][kc][0], bh_[3][kc][1], bh_[3][kc][2], bh_[3][kc][3]};
      uint4 c0v = {bh_[0][kc + 4][0], bh_[0][kc + 4][1], bh_[0][kc + 4][2], bh_[0][kc + 4][3]};
      uint4 c1v = {bh_[1][kc + 4][0], bh_[1][kc + 4][1], bh_[1][kc + 4][2], bh_[1][kc + 4][3]};
      uint4 c2v = {bh_[2][kc + 4][0], bh_[2][kc + 4][1], bh_[2][kc + 4][2], bh_[2][kc + 4][3]};
      uint4 c3v = {bh_[3][kc + 4][0], bh_[3][kc + 4][1], bh_[3][kc + 4][2], bh_[3][kc + 4][3]};
      lB0 = __builtin_amdgcn_mfma_f32_16x16x32_bf16(af, __builtin_bit_cast(bfrag, b0v), lB0, 0, 0, 0);
      lB1 = __builtin_amdgcn_mfma_f32_16x16x32_bf16(af, __builtin_bit_cast(bfrag, b1v), lB1, 0, 0, 0);
      lB2 = __builtin_amdgcn_mfma_f32_16x16x32_bf16(af, __builtin_bit_cast(bfrag, b2v), lB2, 0, 0, 0);
      lB3 = __builtin_amdgcn_mfma_f32_16x16x32_bf16(af, __builtin_bit_cast(bfrag, b3v), lB3, 0, 0, 0);
      uB0 = __builtin_amdgcn_mfma_f32_16x16x32_bf16(af2, __builtin_bit_cast(bfrag, c0v), uB0, 0, 0, 0);
      uB1 = __builtin_amdgcn_mfma_f32_16x16x32_bf16(af2, __builtin_bit_cast(bfrag, c1v), uB1, 0, 0, 0);
      uB2 = __builtin_amdgcn_mfma_f32_16x16x32_bf16(af2, __builtin_bit_cast(bfrag, c2v), uB2, 0, 0, 0);
      uB3 = __builtin_amdgcn_mfma_f32_16x16x32_bf16(af2, __builtin_bit_cast(bfrag, c3v), uB3, 0, 0, 0);
    }
    {
      f32x4 myc = sel4(quad, lB0 + uB0, lB1 + uB1, lB2 + uB2, lB3 + uB3);
#pragma unroll
      for (int m = 0; m < 4; ++m) {
        float xcl = fminf(fmaxf(myc[m] + bhi(xcc[m]), -15.f), 15.f);
        float exv = __expf(2.f * xcl);
        float hc = 1.f - 2.f * __builtin_amdgcn_rcpf(exv + 1.f);
        float gt = gsh[m * 512 + t];
        bool valid = t < len[m];
        float hn = hm[m] + gt * (hc - hm[m]);
        hm[m] = valid ? hn : hm[m];
        hB[m * 272 + cq] = f2b(hm[m]);
        eb[((tt * 4 + m) << 8) + cq] = f2b(valid ? hm[m] : 0.f);
      }
    }
    sync_lds();
  }
#pragma unroll
  for (int k = 0; k < 4; ++k) {
    int i = tid + k * 256;
    uint4 ev = ((const uint4*)eb)[i];
    int sm = i >> 5, jc = i & 31;
    int s = sm >> 2, m = sm & 3;
    ((uint4*)(ep + ((size_t)(b0 + m) * 512 + (504 + s)) * 256))[jc] = ev;
  }
}

// ---------------- final dense: out_s/out_e (fp32 output) ----------------
__global__ void k_out(const unsigned short* __restrict__ ep,
                      const void* __restrict__ Ws,
                      const void* __restrict__ We,
                      const float* __restrict__ qs,
                      const float* __restrict__ qe,
                      const int* __restrict__ mode,
                      float* __restrict__ out) {
  int md = *mode;
  int tid = threadIdx.x;
  int wave = tid >> 6, lane = tid & 63;
  int row = blockIdx.x * 4 + wave;  // (b,t) flat, 0..32767
  const unsigned short* er = ep + (size_t)row * 256 + lane * 4;
  float f0 = b2f(er[0]), f1 = b2f(er[1]), f2 = b2f(er[2]), f3 = b2f(er[3]);
  int n = 256 + lane * 4;
  float s = f0 * ldf(Ws, n, md) + f1 * ldf(Ws, n + 1, md) + f2 * ldf(Ws, n + 2, md) + f3 * ldf(Ws, n + 3, md);
  float e = f0 * ldf(We, n, md) + f1 * ldf(We, n + 1, md) + f2 * ldf(We, n + 2, md) + f3 * ldf(We, n + 3, md);
  for (int o = 32; o > 0; o >>= 1) { s += __shfl_down(s, o); e += __shfl_down(e, o); }
  if (lane == 0) {
    int b = row >> 9;
    out[row] = tanhf(qs[b] + s);
    out[32768 + row] = tanhf(qe[b] + e);
  }
}

extern "C" void kernel_launch(void* const* d_in, const int* in_sizes, int n_in,
                              void* d_out, int out_size, void* d_ws, size_t ws_size,
                              hipStream_t stream) {
  const void* q    = d_in[0];
  const void* fact = d_in[1];
  const int* ilen  = (const int*)d_in[2];
  const void* W1   = d_in[3];
  const void* b1   = d_in[4];
  const void* W2   = d_in[5];
  const void* b2v  = d_in[6];
  const void* Wr   = d_in[7];
  const void* Ur   = d_in[8];
  const void* br   = d_in[9];
  const void* Wh   = d_in[10];
  const void* Uh   = d_in[11];
  const void* bh   = d_in[12];
  const void* Ws   = d_in[13];
  const void* bs   = d_in[14];
  const void* We   = d_in[15];
  const void* be   = d_in[16];

  char* w = (char*)d_ws;
  unsigned* W5q = (unsigned*)(w);
  unsigned* Urp = (unsigned*)(w + 1310720);
  unsigned* Uhp = (unsigned*)(w + 1441792);
  float*    qw1 = (float*)(w + 1572864);
  float*    qs  = (float*)(w + 1638400);
  float*    qe  = (float*)(w + 1638656);
  float*    att = (float*)(w + 1638912);
  float*    g   = (float*)(w + 1769984);
  unsigned* xrh = (unsigned*)(w + 1901056);
  unsigned short* ep = (unsigned short*)(w + 35455488);
  int*      mode = (int*)(w + 52232704);
  float* out = (float*)d_out;

  k_detect<<<dim3(1), dim3(256), 0, stream>>>(fact, mode);
  k_prep_w<<<dim3(128), dim3(256), 0, stream>>>(W1, Wr, Wh, Ur, Uh, mode, W5q, Urp, Uhp);
  k_prep_q<<<dim3(64), dim3(256), 0, stream>>>(q, W1, b1, Ws, bs, We, be, mode, qw1, qs, qe);
  k_main<<<dim3(2048), dim3(256), 0, stream>>>(fact, q, W5q, qw1, W2, b2v, br, bh, mode, att, xrh);
  k_softmax<<<dim3(64), dim3(512), 0, stream>>>(att, g);
  k_scan<<<dim3(16), dim3(256), 0, stream>>>(Urp, Uhp, xrh, g, ilen, ep);
  k_out<<<dim3(8192), dim3(256), 0, stream>>>(ep, Ws, We, qs, qe, mode, out);
}

// Round 12
// 980.467 us; speedup vs baseline: 1.5487x; 1.1728x over previous
//
#include <hip/hip_runtime.h>
#include <cstddef>

// B=64, T=512, H=256. Float inputs fp32 (runtime-detected, bf16 fallback).
// Output fp32: [out_s (B*T), out_e (B*T)].
// ws layout (bytes):
//   0        W5q   640*256 u32 bf16-pair B-frags, uint4-grouped:
//                  idx = ((p>>2)*256+col)*4+(p&3); p: 0..127 W1f, 128..255
//                  W1fq+W1fm, 256..383 W1afq+afm, 384..511 Wr, 512..639 Wh
//   1310720  Urp   128*256 u32  (bf16 pairs along i)
//   1441792  Uhp   128*256 u32
//   1572864  qw1   64*256 f32
//   1638400  qs    64 f32
//   1638656  qe    64 f32
//   1638912  att   64*512 f32
//   1769984  g     64*512 f32
//   1901056  xrh   64*512*256 u32
//   35455488 ep    64*512*256 bf16
//   52232704 mode  int

static __device__ __forceinline__ float b2f(unsigned short u) {
  return __uint_as_float(((unsigned)u) << 16);
}
static __device__ __forceinline__ float blo(unsigned w) { return __uint_as_float(w << 16); }
static __device__ __forceinline__ float bhi(unsigned w) { return __uint_as_float(w & 0xffff0000u); }
static __device__ __forceinline__ unsigned short f2b(float f) {
  unsigned u = __float_as_uint(f);
  u += 0x7fffu + ((u >> 16) & 1u);  // RNE
  return (unsigned short)(u >> 16);
}
static __device__ __forceinline__ float ldf(const void* b, size_t i, int md) {
  return md ? ((const float*)b)[i] : b2f(((const unsigned short*)b)[i]);
}
static __device__ __forceinline__ unsigned short ldb(const void* b, size_t i, int md) {
  return md ? f2b(((const float*)b)[i]) : ((const unsigned short*)b)[i];
}

typedef short bfrag __attribute__((ext_vector_type(8)));
typedef float f32x4 __attribute__((ext_vector_type(4)));

template <int CTRL>
static __device__ __forceinline__ float dpp_add(float x) {
  int v = __builtin_amdgcn_update_dpp(0, __float_as_int(x), CTRL, 0xF, 0xF, true);
  return x + __int_as_float(v);
}
static __device__ __forceinline__ float red16(float x) {
  x = dpp_add<0xB1>(x);
  x = dpp_add<0x4E>(x);
  x = dpp_add<0x141>(x);
  x = dpp_add<0x140>(x);
  return x;
}
static __device__ __forceinline__ void sync_lds() {
  __builtin_amdgcn_fence(__ATOMIC_RELEASE, "workgroup", "local");
  __builtin_amdgcn_s_barrier();
  __builtin_amdgcn_fence(__ATOMIC_ACQUIRE, "workgroup", "local");
}
static __device__ __forceinline__ float fast_tanh(float x) {
  float xc = fminf(fmaxf(x, -15.f), 15.f);
  return 1.f - 2.f * __builtin_amdgcn_rcpf(__expf(2.f * xc) + 1.f);
}

// ---------------- dtype detection ----------------
__global__ void k_detect(const void* __restrict__ fact, int* __restrict__ mode) {
  int tid = threadIdx.x;  // 256
  const unsigned short* u = (const unsigned short*)fact;
  float v = fabsf(b2f(u[2 * tid]));
  if (!(v == v)) v = 1e30f;
  for (int o = 32; o > 0; o >>= 1) v = fmaxf(v, __shfl_xor(v, o));
  __shared__ float red[4];
  int wave = tid >> 6, lane = tid & 63;
  if (lane == 0) red[wave] = v;
  __syncthreads();
  if (tid == 0) {
    float m = fmaxf(fmaxf(red[0], red[1]), fmaxf(red[2], red[3]));
    mode[0] = (m > 1e4f) ? 1 : 0;
  }
}

// ---------------- prep: packed bf16 weights ----------------
__global__ void k_prep_w(const void* __restrict__ W1,
                         const void* __restrict__ Wr,
                         const void* __restrict__ Wh,
                         const void* __restrict__ Ur,
                         const void* __restrict__ Uh,
                         const int* __restrict__ mode,
                         unsigned* __restrict__ W5q,
                         unsigned* __restrict__ Urp,
                         unsigned* __restrict__ Uhp) {
  int md = *mode;
  int idx = blockIdx.x * 256 + threadIdx.x;  // 0..32767
  int i = idx >> 8, j = idx & 255;
  Urp[idx] = (unsigned)ldb(Ur, (size_t)(2 * i) * 256 + j, md) |
             ((unsigned)ldb(Ur, (size_t)(2 * i + 1) * 256 + j, md) << 16);
  Uhp[idx] = (unsigned)ldb(Uh, (size_t)(2 * i) * 256 + j, md) |
             ((unsigned)ldb(Uh, (size_t)(2 * i + 1) * 256 + j, md) << 16);
  float v0, v1;
  int p;
  p = i;
  v0 = ldf(W1, (size_t)(2 * i) * 256 + j, md);
  v1 = ldf(W1, (size_t)(2 * i + 1) * 256 + j, md);
  W5q[(((p >> 2) * 256 + j) << 2) + (p & 3)] = (unsigned)f2b(v0) | ((unsigned)f2b(v1) << 16);
  p = 128 + i;
  v0 = ldf(W1, (size_t)(768 + 2 * i) * 256 + j, md) + ldf(W1, (size_t)(1024 + 2 * i) * 256 + j, md);
  v1 = ldf(W1, (size_t)(769 + 2 * i) * 256 + j, md) + ldf(W1, (size_t)(1025 + 2 * i) * 256 + j, md);
  W5q[(((p >> 2) * 256 + j) << 2) + (p & 3)] = (unsigned)f2b(v0) | ((unsigned)f2b(v1) << 16);
  p = 256 + i;
  v0 = ldf(W1, (size_t)(1280 + 2 * i) * 256 + j, md) + ldf(W1, (size_t)(1536 + 2 * i) * 256 + j, md);
  v1 = ldf(W1, (size_t)(1281 + 2 * i) * 256 + j, md) + ldf(W1, (size_t)(1537 + 2 * i) * 256 + j, md);
  W5q[(((p >> 2) * 256 + j) << 2) + (p & 3)] = (unsigned)f2b(v0) | ((unsigned)f2b(v1) << 16);
  p = 384 + i;
  v0 = ldf(Wr, (size_t)(2 * i) * 256 + j, md);
  v1 = ldf(Wr, (size_t)(2 * i + 1) * 256 + j, md);
  W5q[(((p >> 2) * 256 + j) << 2) + (p & 3)] = (unsigned)f2b(v0) | ((unsigned)f2b(v1) << 16);
  p = 512 + i;
  v0 = ldf(Wh, (size_t)(2 * i) * 256 + j, md);
  v1 = ldf(Wh, (size_t)(2 * i + 1) * 256 + j, md);
  W5q[(((p >> 2) * 256 + j) << 2) + (p & 3)] = (unsigned)f2b(v0) | ((unsigned)f2b(v1) << 16);
}

// ---------------- prep: q-dependent vectors ----------------
__global__ void k_prep_q(const void* __restrict__ q,
                         const void* __restrict__ W1,
                         const void* __restrict__ b1,
                         const void* __restrict__ Ws,
                         const void* __restrict__ bs,
                         const void* __restrict__ We,
                         const void* __restrict__ be,
                         const int* __restrict__ mode,
                         float* __restrict__ qw1,
                         float* __restrict__ qs,
                         float* __restrict__ qe) {
  __shared__ float qsh[256];
  __shared__ float reds[4], rede[4];
  int md = *mode;
  int b = blockIdx.x, tid = threadIdx.x;
  float qv = ldf(q, (size_t)b * 256 + tid, md);
  qsh[tid] = qv;
  __syncthreads();
  float acc = ldf(b1, tid, md);
  for (int i = 0; i < 256; ++i) {
    float w = ldf(W1, (size_t)(256 + i) * 256 + tid, md) + ldf(W1, (size_t)(512 + i) * 256 + tid, md);
    acc = fmaf(qsh[i], w, acc);
  }
  qw1[b * 256 + tid] = acc;
  float ps = qv * ldf(Ws, tid, md);
  float pe = qv * ldf(We, tid, md);
  for (int o = 32; o > 0; o >>= 1) { ps += __shfl_down(ps, o); pe += __shfl_down(pe, o); }
  int wave = tid >> 6, lane = tid & 63;
  if (lane == 0) { reds[wave] = ps; rede[wave] = pe; }
  __syncthreads();
  if (tid == 0) {
    qs[b] = ldf(bs, 0, md) + reds[0] + reds[1] + reds[2] + reds[3];
    qe[b] = ldf(be, 0, md) + rede[0] + rede[1] + rede[2] + rede[3];
  }
}

// ---------------- main GEMM via MFMA: att pre-softmax + xr/xh ----------------
__launch_bounds__(256, 2)
__global__ void k_main(const void* __restrict__ fact,
                       const void* __restrict__ q,
                       const unsigned* __restrict__ W5q,
                       const float* __restrict__ qw1,
                       const void* __restrict__ W2,
                       const void* __restrict__ b2v,
                       const void* __restrict__ br,
                       const void* __restrict__ bh,
                       const int* __restrict__ mode,
                       float* __restrict__ att,
                       unsigned* __restrict__ xrh) {
  __shared__ __align__(16) unsigned short A[16 * 776];
  __shared__ float wsc[64];
  int md = *mode;
  int blk = blockIdx.x;
  int b = blk >> 5, t0 = (blk & 31) * 16;
  int tid = threadIdx.x;
  {
    float qv = ldf(q, (size_t)b * 256 + tid, md);
    for (int r = 0; r < 16; ++r) {
      float f = ldf(fact, ((size_t)(b * 512 + t0 + r)) * 256 + tid, md);
      A[r * 776 + tid] = f2b(f);
      A[r * 776 + 256 + tid] = f2b(f * qv);
      A[r * 776 + 512 + tid] = f2b(fabsf(f - qv));
    }
  }
  __syncthreads();
  int wv = tid >> 6, lane = tid & 63;
  int n16 = lane & 15, quad = lane >> 4;
  int colb = wv * 64 + n16;
  const uint4* W4 = (const uint4*)W5q;
  f32x4 z = {0.f, 0.f, 0.f, 0.f};
  f32x4 u[4] = {z, z, z, z}, ar[4] = {z, z, z, z}, ah[4] = {z, z, z, z};
#pragma unroll
  for (int kc = 0; kc < 8; ++kc) {
    uint4 av = *(const uint4*)((const char*)A + n16 * 1552 + kc * 64 + quad * 16);
    bfrag af = __builtin_bit_cast(bfrag, av);
    int pg = kc * 4 + quad;
#pragma unroll
    for (int tile = 0; tile < 4; ++tile) {
      int col = colb + tile * 16;
      uint4 bu = W4[(size_t)pg * 256 + col];
      uint4 bw = W4[(size_t)(96 + pg) * 256 + col];
      uint4 bv = W4[(size_t)(128 + pg) * 256 + col];
      u[tile] = __builtin_amdgcn_mfma_f32_16x16x32_bf16(af, __builtin_bit_cast(bfrag, bu), u[tile], 0, 0, 0);
      ar[tile] = __builtin_amdgcn_mfma_f32_16x16x32_bf16(af, __builtin_bit_cast(bfrag, bw), ar[tile], 0, 0, 0);
      ah[tile] = __builtin_amdgcn_mfma_f32_16x16x32_bf16(af, __builtin_bit_cast(bfrag, bv), ah[tile], 0, 0, 0);
    }
  }
#pragma unroll
  for (int kc = 8; kc < 24; ++kc) {
    uint4 av = *(const uint4*)((const char*)A + n16 * 1552 + kc * 64 + quad * 16);
    bfrag af = __builtin_bit_cast(bfrag, av);
    int pg = kc * 4 + quad;
#pragma unroll
    for (int tile = 0; tile < 4; ++tile) {
      int col = colb + tile * 16;
      uint4 bu = W4[(size_t)pg * 256 + col];
      u[tile] = __builtin_amdgcn_mfma_f32_16x16x32_bf16(af, __builtin_bit_cast(bfrag, bu), u[tile], 0, 0, 0);
    }
  }
  float qwv[4], w2v[4], brv[4], bhv[4];
#pragma unroll
  for (int tile = 0; tile < 4; ++tile) {
    int col = colb + tile * 16;
    qwv[tile] = qw1[b * 256 + col];
    w2v[tile] = ldf(W2, col, md);
    brv[tile] = ldf(br, col, md);
    bhv[tile] = ldf(bh, col, md);
  }
  float ps[4];
#pragma unroll
  for (int reg = 0; reg < 4; ++reg) {
    float p = 0.f;
#pragma unroll
    for (int tile = 0; tile < 4; ++tile) {
      float hid = fast_tanh(u[tile][reg] + qwv[tile]);
      p = fmaf(hid, w2v[tile], p);
    }
    ps[reg] = red16(p);
  }
  if (n16 == 0) {
#pragma unroll
    for (int reg = 0; reg < 4; ++reg) wsc[wv * 16 + quad * 4 + reg] = ps[reg];
  }
  __syncthreads();
  if (tid < 16) {
    att[b * 512 + t0 + tid] =
        wsc[tid] + wsc[16 + tid] + wsc[32 + tid] + wsc[48 + tid] + ldf(b2v, 0, md);
  }
#pragma unroll
  for (int tile = 0; tile < 4; ++tile) {
    int col = colb + tile * 16;
#pragma unroll
    for (int reg = 0; reg < 4; ++reg) {
      int t = t0 + quad * 4 + reg;
      unsigned v = (unsigned)f2b(ar[tile][reg] + brv[tile]) |
                   ((unsigned)f2b(ah[tile][reg] + bhv[tile]) << 16);
      xrh[((size_t)(b * 512 + t)) * 256 + col] = v;
    }
  }
}

// ---------------- softmax over T per batch ----------------
__global__ void k_softmax(const float* __restrict__ att, float* __restrict__ g) {
  __shared__ float red[8];
  int b = blockIdx.x, tid = threadIdx.x;  // 512 threads
  float v = att[b * 512 + tid];
  float m = v;
  for (int o = 32; o > 0; o >>= 1) m = fmaxf(m, __shfl_xor(m, o));
  int wave = tid >> 6, lane = tid & 63;
  if (lane == 0) red[wave] = m;
  __syncthreads();
  m = red[0];
#pragma unroll
  for (int w = 1; w < 8; ++w) m = fmaxf(m, red[w]);
  float e = __expf(v - m);
  float s = e;
  for (int o = 32; o > 0; o >>= 1) s += __shfl_xor(s, o);
  __syncthreads();
  if (lane == 0) red[wave] = s;
  __syncthreads();
  s = red[0] + red[1] + red[2] + red[3] + red[4] + red[5] + red[6] + red[7];
  g[b * 512 + tid] = e / s;
}

// ---------------- MFMA GRU scan: 4 batches/block, 16 blocks, 8 waves ----------------
// 512 threads = 8 waves (2/SIMD -> MFMA/VALU/LDS latency of one wave hidden by
// the other, m114). Wave wv owns cols [wv*32, wv*32+32) as 2 N-tiles ->
// B-frags 2x8x4x2 = 128 VGPRs. Same verified layouts as round 10:
//   A[m][k]: m=lane&15 (batch m&3 duplicated), k=quad*8+j
//   B[k][n]: n=lane&15, k=quad*8+j (Urp/Uhp packing)
//   C/D: col=lane&15, row=quad*4+reg (batch = reg)
// Owner lanes: quad<2, col cq = wv*32 + quad*16 + n16 (256 cols covered once).
__launch_bounds__(512, 2)
__global__ void k_scan(const unsigned* __restrict__ Urp,
                       const unsigned* __restrict__ Uhp,
                       const unsigned* __restrict__ xrh,
                       const float* __restrict__ g,
                       const int* __restrict__ input_len,
                       unsigned short* __restrict__ ep) {
  __shared__ __align__(16) unsigned short hB[4 * 272];
  __shared__ __align__(16) unsigned short rhB[4 * 272];
  __shared__ float gsh[4 * 512];
  __shared__ __align__(16) unsigned xb[8 * 4 * 256];        // 32 KB
  __shared__ __align__(16) unsigned short eb[8 * 4 * 256];  // 16 KB
  int b0 = blockIdx.x * 4;
  int tid = threadIdx.x;  // 0..511
  int wv = tid >> 6, lane = tid & 63;
  int n16 = lane & 15, quad = lane >> 4;
  unsigned br_[2][8][4], bh_[2][8][4];
#pragma unroll
  for (int tile = 0; tile < 2; ++tile) {
    int col = wv * 32 + tile * 16 + n16;
#pragma unroll
    for (int kc = 0; kc < 8; ++kc) {
#pragma unroll
      for (int w = 0; w < 4; ++w) {
        int p = kc * 16 + quad * 4 + w;
        br_[tile][kc][w] = Urp[(size_t)p * 256 + col];
        bh_[tile][kc][w] = Uhp[(size_t)p * 256 + col];
      }
    }
  }
  for (int i = tid; i < 2048; i += 512)
    gsh[i] = g[(size_t)(b0 + (i >> 9)) * 512 + (i & 511)];
  for (int i = tid; i < 4 * 272; i += 512) { hB[i] = 0; rhB[i] = 0; }
  int len[4];
#pragma unroll
  for (int m = 0; m < 4; ++m) len[m] = input_len[b0 + m];
  float hm[4] = {0.f, 0.f, 0.f, 0.f};  // owner master h (quad<2 only)
  int cq = wv * 32 + quad * 16 + n16;  // owned column when quad<2
  uint4 pf[4];
#pragma unroll
  for (int k = 0; k < 4; ++k) {
    int i = tid + k * 512;
    int s = i >> 8, rem = i & 255, m = rem >> 6, jc = rem & 63;
    pf[k] = ((const uint4*)(xrh + ((size_t)(b0 + m) * 512 + s) * 256))[jc];
  }
  __syncthreads();
  unsigned xcc[4] = {0u, 0u, 0u, 0u};
  for (int t = 0; t < 512; ++t) {
    int tt = t & 7;
    if (tt == 0) {
      if (t != 0) {
#pragma unroll
        for (int k = 0; k < 2; ++k) {
          int i = tid + k * 512;
          uint4 ev = ((const uint4*)eb)[i];
          int sm = i >> 5, jc = i & 31;
          int s = sm >> 2, m = sm & 3;
          ((uint4*)(ep + ((size_t)(b0 + m) * 512 + (t - 8 + s)) * 256))[jc] = ev;
        }
      }
#pragma unroll
      for (int k = 0; k < 4; ++k) ((uint4*)xb)[tid + k * 512] = pf[k];
      sync_lds();
      if (t < 504) {
        int tb = (t >> 3) + 1;
#pragma unroll
        for (int k = 0; k < 4; ++k) {
          int i = tid + k * 512;
          int s = i >> 8, rem = i & 255, m = rem >> 6, jc = rem & 63;
          pf[k] = ((const uint4*)(xrh + ((size_t)(b0 + m) * 512 + tb * 8 + s) * 256))[jc];
        }
      }
    }
    // ---- phase A: rpre = h @ Ur (2 tiles, 2x4 split chains) ----
    if (quad < 2) {
#pragma unroll
      for (int m = 0; m < 4; ++m) xcc[m] = xb[((tt * 4 + m) << 8) + cq];
    }
    f32x4 za = {0.f, 0.f, 0.f, 0.f};
    f32x4 lA0 = za, lA1 = za, uA0 = za, uA1 = za;
#pragma unroll
    for (int kc = 0; kc < 4; ++kc) {
      uint4 av = *(const uint4*)((const char*)hB + (n16 & 3) * 544 + kc * 64 + quad * 16);
      bfrag af = __builtin_bit_cast(bfrag, av);
      uint4 av2 = *(const uint4*)((const char*)hB + (n16 & 3) * 544 + (kc + 4) * 64 + quad * 16);
      bfrag af2 = __builtin_bit_cast(bfrag, av2);
      uint4 b0v = {br_[0][kc][0], br_[0][kc][1], br_[0][kc][2], br_[0][kc][3]};
      uint4 b1v = {br_[1][kc][0], br_[1][kc][1], br_[1][kc][2], br_[1][kc][3]};
      uint4 c0v = {br_[0][kc + 4][0], br_[0][kc + 4][1], br_[0][kc + 4][2], br_[0][kc + 4][3]};
      uint4 c1v = {br_[1][kc + 4][0], br_[1][kc + 4][1], br_[1][kc + 4][2], br_[1][kc + 4][3]};
      lA0 = __builtin_amdgcn_mfma_f32_16x16x32_bf16(af, __builtin_bit_cast(bfrag, b0v), lA0, 0, 0, 0);
      lA1 = __builtin_amdgcn_mfma_f32_16x16x32_bf16(af, __builtin_bit_cast(bfrag, b1v), lA1, 0, 0, 0);
      uA0 = __builtin_amdgcn_mfma_f32_16x16x32_bf16(af2, __builtin_bit_cast(bfrag, c0v), uA0, 0, 0, 0);
      uA1 = __builtin_amdgcn_mfma_f32_16x16x32_bf16(af2, __builtin_bit_cast(bfrag, c1v), uA1, 0, 0, 0);
    }
    if (quad < 2) {
      f32x4 my = quad == 0 ? (lA0 + uA0) : (lA1 + uA1);
#pragma unroll
      for (int m = 0; m < 4; ++m) {
        float e = __expf(-(my[m] + blo(xcc[m])));
        float r = __builtin_amdgcn_rcpf(1.f + e);
        rhB[m * 272 + cq] = f2b(r * hm[m]);
      }
    }
    sync_lds();
    // ---- phase B: hpre = (r*h) @ Uh ----
    f32x4 lB0 = za, lB1 = za, uB0 = za, uB1 = za;
#pragma unroll
    for (int kc = 0; kc < 4; ++kc) {
      uint4 av = *(const uint4*)((const char*)rhB + (n16 & 3) * 544 + kc * 64 + quad * 16);
      bfrag af = __builtin_bit_cast(bfrag, av);
      uint4 av2 = *(const uint4*)((const char*)rhB + (n16 & 3) * 544 + (kc + 4) * 64 + quad * 16);
      bfrag af2 = __builtin_bit_cast(bfrag, av2);
      uint4 b0v = {bh_[0][kc][0], bh_[0][kc][1], bh_[0][kc][2], bh_[0][kc][3]};
      uint4 b1v = {bh_[1][kc][0], bh_[1][kc][1], bh_[1][kc][2], bh_[1][kc][3]};
      uint4 c0v = {bh_[0][kc + 4][0], bh_[0][kc + 4][1], bh_[0][kc + 4][2], bh_[0][kc + 4][3]};
      uint4 c1v = {bh_[1][kc + 4][0], bh_[1][kc + 4][1], bh_[1][kc + 4][2], bh_[1][kc + 4][3]};
      lB0 = __builtin_amdgcn_mfma_f32_16x16x32_bf16(af, __builtin_bit_cast(bfrag, b0v), lB0, 0, 0, 0);
      lB1 = __builtin_amdgcn_mfma_f32_16x16x32_bf16(af, __builtin_bit_cast(bfrag, b1v), lB1, 0, 0, 0);
      uB0 = __builtin_amdgcn_mfma_f32_16x16x32_bf16(af2, __builtin_bit_cast(bfrag, c0v), uB0, 0, 0, 0);
      uB1 = __builtin_amdgcn_mfma_f32_16x16x32_bf16(af2, __builtin_bit_cast(bfrag, c1v), uB1, 0, 0, 0);
    }
    if (quad < 2) {
      f32x4 myc = quad == 0 ? (lB0 + uB0) : (lB1 + uB1);
#pragma unroll
      for (int m = 0; m < 4; ++m) {
        float xcl = fminf(fmaxf(myc[m] + bhi(xcc[m]), -15.f), 15.f);
        float exv = __expf(2.f * xcl);
        float hc = 1.f - 2.f * __builtin_amdgcn_rcpf(exv + 1.f);
        float gt = gsh[m * 512 + t];
        bool valid = t < len[m];
        float hn = hm[m] + gt * (hc - hm[m]);
        hm[m] = valid ? hn : hm[m];
        hB[m * 272 + cq] = f2b(hm[m]);
        eb[((tt * 4 + m) << 8) + cq] = f2b(valid ? hm[m] : 0.f);
      }
    }
    sync_lds();
  }
#pragma unroll
  for (int k = 0; k < 2; ++k) {
    int i = tid + k * 512;
    uint4 ev = ((const uint4*)eb)[i];
    int sm = i >> 5, jc = i & 31;
    int s = sm >> 2, m = sm & 3;
    ((uint4*)(ep + ((size_t)(b0 + m) * 512 + (504 + s)) * 256))[jc] = ev;
  }
}

// ---------------- final dense: out_s/out_e (fp32 output) ----------------
__global__ void k_out(const unsigned short* __restrict__ ep,
                      const void* __restrict__ Ws,
                      const void* __restrict__ We,
                      const float* __restrict__ qs,
                      const float* __restrict__ qe,
                      const int* __restrict__ mode,
                      float* __restrict__ out) {
  int md = *mode;
  int tid = threadIdx.x;
  int wave = tid >> 6, lane = tid & 63;
  int row = blockIdx.x * 4 + wave;  // (b,t) flat, 0..32767
  const unsigned short* er = ep + (size_t)row * 256 + lane * 4;
  float f0 = b2f(er[0]), f1 = b2f(er[1]), f2 = b2f(er[2]), f3 = b2f(er[3]);
  int n = 256 + lane * 4;
  float s = f0 * ldf(Ws, n, md) + f1 * ldf(Ws, n + 1, md) + f2 * ldf(Ws, n + 2, md) + f3 * ldf(Ws, n + 3, md);
  float e = f0 * ldf(We, n, md) + f1 * ldf(We, n + 1, md) + f2 * ldf(We, n + 2, md) + f3 * ldf(We, n + 3, md);
  for (int o = 32; o > 0; o >>= 1) { s += __shfl_down(s, o); e += __shfl_down(e, o); }
  if (lane == 0) {
    int b = row >> 9;
    out[row] = tanhf(qs[b] + s);
    out[32768 + row] = tanhf(qe[b] + e);
  }
}

extern "C" void kernel_launch(void* const* d_in, const int* in_sizes, int n_in,
                              void* d_out, int out_size, void* d_ws, size_t ws_size,
                              hipStream_t stream) {
  const void* q    = d_in[0];
  const void* fact = d_in[1];
  const int* ilen  = (const int*)d_in[2];
  const void* W1   = d_in[3];
  const void* b1   = d_in[4];
  const void* W2   = d_in[5];
  const void* b2v  = d_in[6];
  const void* Wr   = d_in[7];
  const void* Ur   = d_in[8];
  const void* br   = d_in[9];
  const void* Wh   = d_in[10];
  const void* Uh   = d_in[11];
  const void* bh   = d_in[12];
  const void* Ws   = d_in[13];
  const void* bs   = d_in[14];
  const void* We   = d_in[15];
  const void* be   = d_in[16];

  char* w = (char*)d_ws;
  unsigned* W5q = (unsigned*)(w);
  unsigned* Urp = (unsigned*)(w + 1310720);
  unsigned* Uhp = (unsigned*)(w + 1441792);
  float*    qw1 = (float*)(w + 1572864);
  float*    qs  = (float*)(w + 1638400);
  float*    qe  = (float*)(w + 1638656);
  float*    att = (float*)(w + 1638912);
  float*    g   = (float*)(w + 1769984);
  unsigned* xrh = (unsigned*)(w + 1901056);
  unsigned short* ep = (unsigned short*)(w + 35455488);
  int*      mode = (int*)(w + 52232704);
  float* out = (float*)d_out;

  k_detect<<<dim3(1), dim3(256), 0, stream>>>(fact, mode);
  k_prep_w<<<dim3(128), dim3(256), 0, stream>>>(W1, Wr, Wh, Ur, Uh, mode, W5q, Urp, Uhp);
  k_prep_q<<<dim3(64), dim3(256), 0, stream>>>(q, W1, b1, Ws, bs, We, be, mode, qw1, qs, qe);
  k_main<<<dim3(2048), dim3(256), 0, stream>>>(fact, q, W5q, qw1, W2, b2v, br, bh, mode, att, xrh);
  k_softmax<<<dim3(64), dim3(512), 0, stream>>>(att, g);
  k_scan<<<dim3(16), dim3(512), 0, stream>>>(Urp, Uhp, xrh, g, ilen, ep);
  k_out<<<dim3(8192), dim3(256), 0, stream>>>(ep, Ws, We, qs, qe, mode, out);
}